// Round 4
// baseline (1188.834 us; speedup 1.0000x reference)
//
#include <hip/hip_runtime.h>

// GCN layer on MI355X — round 13: CSR-free edge-parallel gather.
//   M1:  memsetAsync(bhist+gcurz, 0, 2KB)
//   K1 prep_hist:      Wsw swizzle + BN consts (blocks 0-63) FUSED with
//                      bucket histogram (all 391 blocks)
//   K2 scatter_linear: bucket_scatter (391) FUSED with linear_mfma (1563).
//                      ebuf now PACKED int: (src<<9)|dst_local (17+9 bits),
//                      6.4MB. h GROUP-MAJOR [8][NN][16] bf16, LDS-staged
//                      contiguous stores (r12-proven).
//   K3 (bucket_to_csr) DELETED — csr/off buffers gone. The bucket segment
//                      already groups all edges of its 391 dsts.
//   K4 gather_bn_relu: block = bucket b x group g (2048 blocks, g=bid&7 ->
//                      XCD, h slice 3.2MB L2-resident, PROVEN). Edge-
//                      parallel: one edge per lane (coalesced 4B packed
//                      read + 32B h[src] read), ds_add_f32 into
//                      acc[391][17] (+dcnt -> exact degree). No divergence,
//                      no per-node serial loops, no CSR staging. Finalize:
//                      BN+ReLU from LDS, fully coalesced float4 stores.
//                      r12 failed at 80.5us with 35% VALU / 56% occ —
//                      divergence + dependent chains, not traffic (FETCH
//                      59MB). This kills both.
// ws NEED = 32.04MB (<= proven 32.8MB); atomic fallback below that.
// mean(h[src]) = mean(x[src])@W + b (linearity); deg=0 -> sum=0 -> relu(sh).
// LDS f32 atomics make summation order nondeterministic: |delta| << 1e-3,
// well inside the absmax threshold (bf16 quantization already 0.0078).

#define NN 100000
#define NE 1600000
#define CC 128
#define BN_EPS 1e-5f
#define LBLK 1563     // ceil(NN/64) linear blocks
#define LSTR 136      // LDS row stride in bf16 (128 + 8 pad)
#define NBUK 256      // dst buckets
#define DPB 391       // dsts per bucket (256*391 = 100096 >= NN)
#define ACH 4096      // edges per scatter block
#define ABLK 391      // ceil(NE/ACH)

typedef __attribute__((ext_vector_type(8))) short bf16x8;
typedef __attribute__((ext_vector_type(4))) float f32x4;

static __device__ __forceinline__ short f2bf(float f) {
  union { float f; unsigned u; } v; v.f = f;
  unsigned r = (v.u + 0x7FFF + ((v.u >> 16) & 1)) >> 16;  // RNE
  return (short)r;
}
static __device__ __forceinline__ float bflo(unsigned p) {
  return __uint_as_float(p << 16);
}
static __device__ __forceinline__ float bfhi(unsigned p) {
  return __uint_as_float(p & 0xffff0000u);
}

// 256-wide Hillis-Steele scan in LDS; leaves a[] exclusive, returns excl[t].
// (256-thread blocks only.)
static __device__ __forceinline__ int excl_scan256(int* a, int t, int v) {
  a[t] = v;
  __syncthreads();
  for (int d = 1; d < 256; d <<= 1) {
    const int x = (t >= d) ? a[t - d] : 0;
    __syncthreads();
    a[t] += x;
    __syncthreads();
  }
  const int incl = a[t];
  __syncthreads();
  a[t] = incl - v;
  __syncthreads();
  return incl - v;
}

// ---------------------------------------------------------------------------
// K1: prep (Wsw swizzle, col-permuted so D-lane m holds natural cols m*8..+7;
// BN scale/shift + bias) on blocks 0-63, bucket histogram on all 391 blocks.
// bhist pre-zeroed by the M1 memset.
// ---------------------------------------------------------------------------
__global__ __launch_bounds__(256) void prep_hist(
    const float* __restrict__ W, const float* __restrict__ bias,
    const float* __restrict__ gamma, const float* __restrict__ beta,
    const float* __restrict__ rmean, const float* __restrict__ rvar,
    const int* __restrict__ ei, short* __restrict__ Wsw,
    float* __restrict__ scsh, int* __restrict__ bhist) {
  __shared__ int lh[NBUK];
  const int t = threadIdx.x;
  const int i = blockIdx.x * 256 + t;
  if (i < CC * CC) {
    const int k = i >> 7, n = i & 127;
    const int nt = n & 7, m = n >> 3;
    const int kb = k >> 5, q = (k >> 3) & 3, j = k & 7;
    Wsw[(size_t)(((nt * 4 + kb) * 64 + (m + 16 * q)) * 8 + j)] = f2bf(W[i]);
  }
  if (i < CC) {
    const float sc = gamma[i] * rsqrtf(rvar[i] + BN_EPS);
    scsh[i] = sc;
    scsh[CC + i] = beta[i] - rmean[i] * sc;
    scsh[2 * CC + i] = bias[i];
  }
  lh[t] = 0;
  __syncthreads();
  const int e0 = blockIdx.x * ACH;
  const int e1 = min(NE, e0 + ACH);
  for (int e = e0 + t; e < e1; e += 256) atomicAdd(&lh[ei[NE + e] / DPB], 1);
  __syncthreads();
  if (lh[t]) atomicAdd(&bhist[t], lh[t]);
}

// ---------------------------------------------------------------------------
// K2: blocks [0,scat): bucket_scatter — chunk-sort 4096 edges by bucket in
// LDS, reserve contiguous global runs, write PACKED ebuf coalesced:
// (src<<9)|dst_local. blocks [scat,..): linear_mfma — h = bf16(x@W+b),
// LDS-staged input, MFMA, output tile re-staged in LDS, stored as per-group
// contiguous runs.
// ---------------------------------------------------------------------------
__global__ __launch_bounds__(256) void scatter_linear(
    const int* __restrict__ ei, const int* __restrict__ bhist,
    int* __restrict__ gcurz, int* __restrict__ ebuf,
    const float* __restrict__ x, const short* __restrict__ Wsw,
    const float* __restrict__ scsh, short* __restrict__ hout,
    int scat) {
  __shared__ int2 sorted[ACH];  // 32 KB (linear role aliases as bf16 tile)
  __shared__ int gsc[NBUK], lh[NBUK], lex[NBUK], rb[NBUK], lc[NBUK];
  const int t = threadIdx.x;

  if (blockIdx.x < scat) {
    // ----- scatter role -----
    const int e0 = blockIdx.x * ACH;
    const int e1 = min(NE, e0 + ACH);
    const int gbase = excl_scan256(gsc, t, bhist[t]);
    lh[t] = 0;
    __syncthreads();
    for (int e = e0 + t; e < e1; e += 256) atomicAdd(&lh[ei[NE + e] / DPB], 1);
    __syncthreads();
    const int vh = lh[t];
    const int lbase = excl_scan256(lex, t, vh);
    lc[t] = lbase;
    if (vh > 0) rb[t] = gbase + atomicAdd(&gcurz[t], vh);
    __syncthreads();
    for (int e = e0 + t; e < e1; e += 256) {
      const int src = ei[e], dst = ei[NE + e];
      const int p = atomicAdd(&lc[dst / DPB], 1);
      sorted[p] = make_int2(src, dst);
    }
    __syncthreads();
    const int n = e1 - e0;
    for (int i = t; i < n; i += 256) {
      const int2 v = sorted[i];
      const int b = v.y / DPB;
      ebuf[rb[b] + (i - lex[b])] = (v.x << 9) | (v.y - b * DPB);
    }
    return;
  }

  // ----- linear role -----
  short* lsA = (short*)sorted;  // 64*LSTR*2 = 17.4 KB <= 32 KB
  const int n0 = (blockIdx.x - scat) * 64;

#pragma unroll
  for (int j = 0; j < 8; ++j) {
    const int idx = j * 256 + t;
    const int row = idx >> 5, kc4 = idx & 31;
    float4 v = make_float4(0.f, 0.f, 0.f, 0.f);
    if (n0 + row < NN) v = *(const float4*)(x + (size_t)(n0 + row) * CC + kc4 * 4);
    short4 sv;
    sv.x = f2bf(v.x); sv.y = f2bf(v.y); sv.z = f2bf(v.z); sv.w = f2bf(v.w);
    *(short4*)(lsA + row * LSTR + kc4 * 4) = sv;
  }
  __syncthreads();

  const int wave = t >> 6, lane = t & 63;
  const int quad = lane >> 4, m = lane & 15;

  f32x4 acc[8];
#pragma unroll
  for (int nt = 0; nt < 8; ++nt) acc[nt] = (f32x4){0.f, 0.f, 0.f, 0.f};

#pragma unroll
  for (int kb = 0; kb < 4; ++kb) {
    const bf16x8 a =
        *(const bf16x8*)(lsA + (wave * 16 + m) * LSTR + kb * 32 + quad * 8);
#pragma unroll
    for (int nt = 0; nt < 8; ++nt) {
      bf16x8 bb = *(const bf16x8*)(Wsw + (size_t)(((nt * 4 + kb) * 64 + lane) * 8));
      acc[nt] = __builtin_amdgcn_mfma_f32_16x16x32_bf16(a, bb, acc[nt], 0, 0, 0);
    }
  }

  const float4 b0 = *(const float4*)(scsh + 2 * CC + m * 8);
  const float4 b1 = *(const float4*)(scsh + 2 * CC + m * 8 + 4);
  const float bv[8] = {b0.x, b0.y, b0.z, b0.w, b1.x, b1.y, b1.z, b1.w};

  __syncthreads();  // all A-tile reads done; reuse lsA for the output tile

  // stage bf16 output tile [64][LSTR]: lane m holds natural cols m*8..+7
#pragma unroll
  for (int reg = 0; reg < 4; ++reg) {
    const int r = wave * 16 + quad * 4 + reg;  // local row 0..63
    bf16x8 hv;
#pragma unroll
    for (int nt = 0; nt < 8; ++nt) hv[nt] = f2bf(acc[nt][reg] + bv[nt]);
    *(bf16x8*)(lsA + r * LSTR + m * 8) = hv;
  }
  __syncthreads();

  // copy out: per group g, rows of 16 bf16 are contiguous in h[g][node][16]
  // -> 2KB contiguous runs. 2 groups per round, 128 threads per group.
#pragma unroll
  for (int rr = 0; rr < 4; ++rr) {
    const int g2 = rr * 2 + (t >> 7);
    const int idx = t & 127;
    const int row = idx >> 1, half = idx & 1;
    const int R = n0 + row;
    if (R < NN) {
      bf16x8 v = *(const bf16x8*)(lsA + row * LSTR + g2 * 16 + half * 8);
      *(bf16x8*)(hout + (size_t)g2 * (NN * 16) + (size_t)R * 16 + half * 8) = v;
    }
  }
}

// ---------------------------------------------------------------------------
// K4: CSR-free edge-parallel gather. block = (bucket b, group g); g = bid&7
// -> XCD (h slice 3.2MB resident in that XCD's L2). Bucket segment holds ALL
// edges of its 391 dsts -> dcnt is the exact degree. One edge per lane:
// coalesced packed-int read, 32B h[src] read, 16x ds_add_f32 into
// acc[dl][17-stride] (odd stride spreads banks) + dcnt. Finalize = BN+ReLU
// from LDS, coalesced float4 stores.
// ---------------------------------------------------------------------------
__global__ __launch_bounds__(256) void gather_bn_relu(
    const short* __restrict__ h, const int* __restrict__ ebuf,
    const int* __restrict__ bhist, const float* __restrict__ scsh,
    float* __restrict__ out) {
  __shared__ float acc[DPB][17];  // 26.0 KB, odd stride -> bank spread
  __shared__ int dcnt[DPB];
  __shared__ int gs[NBUK];
  const int g = blockIdx.x & 7;
  const int b = blockIdx.x >> 3;
  const int t = threadIdx.x;

  excl_scan256(gs, t, bhist[t]);
  const int segbase = gs[b];
  const int seglen = bhist[b];

  float* af = &acc[0][0];
  for (int i = t; i < DPB * 17; i += 256) af[i] = 0.f;
  for (int i = t; i < DPB; i += 256) dcnt[i] = 0;
  __syncthreads();

  const short* hg = h + (size_t)g * (NN * 16);
  const int e1 = segbase + seglen;
  for (int i = segbase + t; i < e1; i += 256) {
    const unsigned e = (unsigned)ebuf[i];
    const int src = e >> 9;
    const int dl = e & 511;
    const uint4 p = *(const uint4*)(hg + (size_t)src * 16);
    const uint4 q = *(const uint4*)(hg + (size_t)src * 16 + 8);
    float* ar = acc[dl];
    atomicAdd(ar + 0,  bflo(p.x)); atomicAdd(ar + 1,  bfhi(p.x));
    atomicAdd(ar + 2,  bflo(p.y)); atomicAdd(ar + 3,  bfhi(p.y));
    atomicAdd(ar + 4,  bflo(p.z)); atomicAdd(ar + 5,  bfhi(p.z));
    atomicAdd(ar + 6,  bflo(p.w)); atomicAdd(ar + 7,  bfhi(p.w));
    atomicAdd(ar + 8,  bflo(q.x)); atomicAdd(ar + 9,  bfhi(q.x));
    atomicAdd(ar + 10, bflo(q.y)); atomicAdd(ar + 11, bfhi(q.y));
    atomicAdd(ar + 12, bflo(q.z)); atomicAdd(ar + 13, bfhi(q.z));
    atomicAdd(ar + 14, bflo(q.w)); atomicAdd(ar + 15, bfhi(q.w));
    atomicAdd(&dcnt[dl], 1);
  }
  __syncthreads();

  const int lo = b * DPB;
  const int nd = min(NN - lo, DPB);
  for (int idx = t; idx < nd * 4; idx += 256) {
    const int l = idx >> 2, q4 = idx & 3;
    const int c = dcnt[l];
    const float inv = (c > 0) ? 1.0f / (float)c : 0.0f;
    const int col = g * 16 + q4 * 4;
    const float4 sc = *(const float4*)(scsh + col);
    const float4 sh = *(const float4*)(scsh + CC + col);
    float4 o;
    o.x = fmaxf(0.f, acc[l][q4 * 4 + 0] * inv * sc.x + sh.x);
    o.y = fmaxf(0.f, acc[l][q4 * 4 + 1] * inv * sc.y + sh.y);
    o.z = fmaxf(0.f, acc[l][q4 * 4 + 2] * inv * sc.z + sh.z);
    o.w = fmaxf(0.f, acc[l][q4 * 4 + 3] * inv * sc.w + sh.w);
    *(float4*)(out + (size_t)(lo + l) * CC + col) = o;
  }
}

// ---------------------------------------------------------------------------
// Fallback (small ws): atomic scatter + fp32 vector GEMM.
// ---------------------------------------------------------------------------
__global__ __launch_bounds__(256) void edge_scatter(
    const float* __restrict__ x, const int* __restrict__ ei,
    float* __restrict__ sums, int* __restrict__ cnt) {
  int gt = blockIdx.x * 256 + threadIdx.x;
  int e = gt >> 5;
  int sub = gt & 31;
  if (e >= NE) return;
  int src = ei[e];
  int dst = ei[NE + e];
  const float4 v = *(const float4*)(x + (size_t)src * CC + sub * 4);
  float* o = sums + (size_t)dst * CC + sub * 4;
  unsafeAtomicAdd(o + 0, v.x);
  unsafeAtomicAdd(o + 1, v.y);
  unsafeAtomicAdd(o + 2, v.z);
  unsafeAtomicAdd(o + 3, v.w);
  if (sub == 0) atomicAdd(cnt + dst, 1);
}

__global__ __launch_bounds__(256) void gemm_bn_relu_fb(
    float* buf, const float* __restrict__ W, const float* __restrict__ bias,
    const float* __restrict__ gamma, const float* __restrict__ beta,
    const float* __restrict__ rmean, const float* __restrict__ rvar,
    const int* __restrict__ cnt) {
  __shared__ float xsT[CC][65];
  const int t = threadIdx.x;
  const int n0 = blockIdx.x * 64;
  for (int j = 0; j < 8; ++j) {
    int i = t + 256 * j;
    int row = i >> 5;
    int ko = (i & 31) * 4;
    float4 v = make_float4(0.f, 0.f, 0.f, 0.f);
    if (n0 + row < NN) v = *(const float4*)(buf + (size_t)(n0 + row) * CC + ko);
    xsT[ko + 0][row] = v.x;
    xsT[ko + 1][row] = v.y;
    xsT[ko + 2][row] = v.z;
    xsT[ko + 3][row] = v.w;
  }
  __syncthreads();
  const int cg = t & 31;
  const int ng8 = (t >> 5) * 8;
  float acc[8][4];
#pragma unroll
  for (int j = 0; j < 8; ++j)
#pragma unroll
    for (int c = 0; c < 4; ++c) acc[j][c] = 0.f;
#pragma unroll 8
  for (int k = 0; k < CC; ++k) {
    const float4 wv = *(const float4*)(W + k * CC + cg * 4);
#pragma unroll
    for (int j = 0; j < 8; ++j) {
      const float xv = xsT[k][ng8 + j];
      acc[j][0] = fmaf(xv, wv.x, acc[j][0]);
      acc[j][1] = fmaf(xv, wv.y, acc[j][1]);
      acc[j][2] = fmaf(xv, wv.z, acc[j][2]);
      acc[j][3] = fmaf(xv, wv.w, acc[j][3]);
    }
  }
  const float4 bb = *(const float4*)(bias + cg * 4);
  const float4 gg = *(const float4*)(gamma + cg * 4);
  const float4 bt = *(const float4*)(beta + cg * 4);
  const float4 mu = *(const float4*)(rmean + cg * 4);
  const float4 vr = *(const float4*)(rvar + cg * 4);
  float sc[4], sh[4];
  sc[0] = gg.x * rsqrtf(vr.x + BN_EPS);
  sc[1] = gg.y * rsqrtf(vr.y + BN_EPS);
  sc[2] = gg.z * rsqrtf(vr.z + BN_EPS);
  sc[3] = gg.w * rsqrtf(vr.w + BN_EPS);
  sh[0] = bt.x - mu.x * sc[0];
  sh[1] = bt.y - mu.y * sc[1];
  sh[2] = bt.z - mu.z * sc[2];
  sh[3] = bt.w - mu.w * sc[3];
#pragma unroll
  for (int j = 0; j < 8; ++j) {
    const int n = n0 + ng8 + j;
    if (n >= NN) continue;
    const int cn = cnt[n];
    const float inv = cn > 0 ? 1.0f / (float)cn : 0.0f;
    const float bsel = cn > 0 ? 1.0f : 0.0f;
    float4 o;
    o.x = fmaxf(0.f, (acc[j][0] * inv + bsel * bb.x) * sc[0] + sh[0]);
    o.y = fmaxf(0.f, (acc[j][1] * inv + bsel * bb.y) * sc[1] + sh[1]);
    o.z = fmaxf(0.f, (acc[j][2] * inv + bsel * bb.z) * sc[2] + sh[2]);
    o.w = fmaxf(0.f, (acc[j][3] * inv + bsel * bb.w) * sc[3] + sh[3]);
    *(float4*)(buf + (size_t)n * CC + cg * 4) = o;
  }
}

extern "C" void kernel_launch(void* const* d_in, const int* in_sizes, int n_in,
                              void* d_out, int out_size, void* d_ws, size_t ws_size,
                              hipStream_t stream) {
  const float* x     = (const float*)d_in[0];
  const int*   ei    = (const int*)d_in[1];
  const float* W     = (const float*)d_in[2];
  const float* bias  = (const float*)d_in[3];
  const float* gamma = (const float*)d_in[4];
  const float* beta  = (const float*)d_in[5];
  const float* rmean = (const float*)d_in[6];
  const float* rvar  = (const float*)d_in[7];
  float* out = (float*)d_out;

  // ws layout (bytes):
  //   bhist[256] | gcurz[256] (contiguous -> one 2KB memset)
  //   | scsh[384f] | Wsw[16384 bf16] | ebuf int[NE] | h[NN*CC bf16]
  const size_t BH_B   = 0;
  const size_t GC_B   = 1024;
  const size_t SCSH_B = 2048;
  const size_t WSW_B  = 3584;
  const size_t EB_B   = 36352;
  const size_t H_B    = EB_B + (size_t)NE * 4;        // 6,436,352
  const size_t NEED   = H_B + (size_t)NN * CC * 2;    // 32,036,352

  if (ws_size >= NEED) {
    int*   bhist = (int*)((char*)d_ws + BH_B);
    int*   gcurz = (int*)((char*)d_ws + GC_B);
    float* scsh  = (float*)((char*)d_ws + SCSH_B);
    short* Wsw   = (short*)((char*)d_ws + WSW_B);
    int*   ebuf  = (int*)((char*)d_ws + EB_B);
    short* h     = (short*)((char*)d_ws + H_B);

    hipMemsetAsync(bhist, 0, 2048, stream);  // bhist + gcurz
    prep_hist<<<ABLK, 256, 0, stream>>>(W, bias, gamma, beta, rmean, rvar,
                                        ei, Wsw, scsh, bhist);
    scatter_linear<<<ABLK + LBLK, 256, 0, stream>>>(
        ei, bhist, gcurz, ebuf, x, Wsw, scsh, h, ABLK);
    gather_bn_relu<<<NBUK * 8, 256, 0, stream>>>(h, ebuf, bhist, scsh, out);
  } else {
    int* cnt = (int*)d_ws;
    hipMemsetAsync(out, 0, (size_t)NN * CC * sizeof(float), stream);
    hipMemsetAsync(cnt, 0, (size_t)NN * sizeof(int), stream);
    edge_scatter<<<(NE * 32) / 256, 256, 0, stream>>>(x, ei, out, cnt);
    gemm_bn_relu_fb<<<(NN + 63) / 64, 256, 0, stream>>>(
        out, W, bias, gamma, beta, rmean, rvar, cnt);
  }
}

// Round 5
// 296.885 us; speedup vs baseline: 4.0044x; 4.0044x over previous
//
#include <hip/hip_runtime.h>

// GCN layer on MI355X — round 14: 8-edge-parallel sliced gather (r13's LDS
// atomics were a disaster: 190cy/ds_add, VALUBusy 1.25%. Reverted to the
// r12 pipeline, new K4 geometry).
//   M1:  memsetAsync(bhist+gcurz, 0, 2KB)
//   K1 prep_hist:      Wsw swizzle + BN consts FUSED with bucket histogram
//   K2 scatter_linear: bucket_scatter (391) FUSED with linear_mfma (1563);
//                      h GROUP-MAJOR [8][NN][16] bf16, LDS-staged stores.
//   K3 bucket_to_csr:  1024 threads/block (r11-proven).
//   K4 gather_bn_relu: block = 256 nodes x group g (g=bid&7 -> XCD; slice
//                      3.2MB L2-resident, PROVEN FETCH 179->60MB). Wave
//                      processes ONE node at a time (64 nodes serial):
//                      lane=(e=lane&7, c=lane>>3): one VMEM instr = 8 edges
//                      x 32B = full 256B -> 8 edge-visits/instr, total VMEM
//                      = NE = 1.6M instrs (HALF of r8's 3.2M @71.7us).
//                      Zero divergence (wave-uniform trip count), csr from
//                      LDS (LGKM pipe), reduce over e via xor 1/2/4 only
//                      (32-lane-local, no bpermute), unroll 2 for ILP.
// Accounting: VMEM 1.6M instrs ~25us; VALU/DS ~30us overlapped; traffic
// 60MB ~18us -> predict ~45us (r8 71.7 / r12 80.5).
// mean(h[src]) = mean(x[src])@W + b (linearity); deg=0 -> sum=0 -> relu(sh).

#define NN 100000
#define NE 1600000
#define CC 128
#define BN_EPS 1e-5f
#define LBLK 1563     // ceil(NN/64) linear blocks
#define LSTR 136      // LDS row stride in bf16 (128 + 8 pad)
#define NBUK 256      // dst buckets
#define DPB 391       // dsts per bucket (256*391 = 100096 >= NN)
#define ACH 4096      // edges per scatter block
#define ABLK 391      // ceil(NE/ACH)
#define CAP 10240     // to_csr LDS segment capacity (mean 6250, huge margin)
#define GNB 256       // nodes per gather block
#define CAP2 5120     // gather csr LDS capacity (mean 4096, std 64: +16sigma)

typedef __attribute__((ext_vector_type(8))) short bf16x8;
typedef __attribute__((ext_vector_type(4))) float f32x4;

static __device__ __forceinline__ short f2bf(float f) {
  union { float f; unsigned u; } v; v.f = f;
  unsigned r = (v.u + 0x7FFF + ((v.u >> 16) & 1)) >> 16;  // RNE
  return (short)r;
}
static __device__ __forceinline__ float bflo(unsigned p) {
  return __uint_as_float(p << 16);
}
static __device__ __forceinline__ float bfhi(unsigned p) {
  return __uint_as_float(p & 0xffff0000u);
}

// 256-wide Hillis-Steele scan in LDS; leaves a[] exclusive, returns excl[t].
// (256-thread blocks only.)
static __device__ __forceinline__ int excl_scan256(int* a, int t, int v) {
  a[t] = v;
  __syncthreads();
  for (int d = 1; d < 256; d <<= 1) {
    const int x = (t >= d) ? a[t - d] : 0;
    __syncthreads();
    a[t] += x;
    __syncthreads();
  }
  const int incl = a[t];
  __syncthreads();
  a[t] = incl - v;
  __syncthreads();
  return incl - v;
}

// ---------------------------------------------------------------------------
// K1: prep (Wsw swizzle, col-permuted so D-lane m holds natural cols m*8..+7;
// BN scale/shift + bias) on blocks 0-63, bucket histogram on all 391 blocks.
// bhist pre-zeroed by the M1 memset.
// ---------------------------------------------------------------------------
__global__ __launch_bounds__(256) void prep_hist(
    const float* __restrict__ W, const float* __restrict__ bias,
    const float* __restrict__ gamma, const float* __restrict__ beta,
    const float* __restrict__ rmean, const float* __restrict__ rvar,
    const int* __restrict__ ei, short* __restrict__ Wsw,
    float* __restrict__ scsh, int* __restrict__ bhist) {
  __shared__ int lh[NBUK];
  const int t = threadIdx.x;
  const int i = blockIdx.x * 256 + t;
  if (i < CC * CC) {
    const int k = i >> 7, n = i & 127;
    const int nt = n & 7, m = n >> 3;
    const int kb = k >> 5, q = (k >> 3) & 3, j = k & 7;
    Wsw[(size_t)(((nt * 4 + kb) * 64 + (m + 16 * q)) * 8 + j)] = f2bf(W[i]);
  }
  if (i < CC) {
    const float sc = gamma[i] * rsqrtf(rvar[i] + BN_EPS);
    scsh[i] = sc;
    scsh[CC + i] = beta[i] - rmean[i] * sc;
    scsh[2 * CC + i] = bias[i];
  }
  lh[t] = 0;
  __syncthreads();
  const int e0 = blockIdx.x * ACH;
  const int e1 = min(NE, e0 + ACH);
  for (int e = e0 + t; e < e1; e += 256) atomicAdd(&lh[ei[NE + e] / DPB], 1);
  __syncthreads();
  if (lh[t]) atomicAdd(&bhist[t], lh[t]);
}

// ---------------------------------------------------------------------------
// K2: blocks [0,scat): bucket_scatter — chunk-sort 4096 edges by bucket in
// LDS, reserve contiguous global runs, write ebuf coalesced. blocks
// [scat,..): linear_mfma — h = bf16(x@W+b), LDS-staged input, MFMA, then
// output tile re-staged in LDS and stored as per-group contiguous runs.
// ---------------------------------------------------------------------------
__global__ __launch_bounds__(256) void scatter_linear(
    const int* __restrict__ ei, const int* __restrict__ bhist,
    int* __restrict__ gcurz, int2* __restrict__ ebuf,
    const float* __restrict__ x, const short* __restrict__ Wsw,
    const float* __restrict__ scsh, short* __restrict__ hout,
    int scat) {
  __shared__ int2 sorted[ACH];  // 32 KB (linear role aliases as bf16 tile)
  __shared__ int gsc[NBUK], lh[NBUK], lex[NBUK], rb[NBUK], lc[NBUK];
  const int t = threadIdx.x;

  if (blockIdx.x < scat) {
    // ----- scatter role -----
    const int e0 = blockIdx.x * ACH;
    const int e1 = min(NE, e0 + ACH);
    const int gbase = excl_scan256(gsc, t, bhist[t]);
    lh[t] = 0;
    __syncthreads();
    for (int e = e0 + t; e < e1; e += 256) atomicAdd(&lh[ei[NE + e] / DPB], 1);
    __syncthreads();
    const int vh = lh[t];
    const int lbase = excl_scan256(lex, t, vh);
    lc[t] = lbase;
    if (vh > 0) rb[t] = gbase + atomicAdd(&gcurz[t], vh);
    __syncthreads();
    for (int e = e0 + t; e < e1; e += 256) {
      const int src = ei[e], dst = ei[NE + e];
      const int p = atomicAdd(&lc[dst / DPB], 1);
      sorted[p] = make_int2(src, dst);
    }
    __syncthreads();
    const int n = e1 - e0;
    for (int i = t; i < n; i += 256) {
      const int2 v = sorted[i];
      const int b = v.y / DPB;
      ebuf[rb[b] + (i - lex[b])] = v;
    }
    return;
  }

  // ----- linear role -----
  short* lsA = (short*)sorted;  // 64*LSTR*2 = 17.4 KB <= 32 KB
  const int n0 = (blockIdx.x - scat) * 64;

#pragma unroll
  for (int j = 0; j < 8; ++j) {
    const int idx = j * 256 + t;
    const int row = idx >> 5, kc4 = idx & 31;
    float4 v = make_float4(0.f, 0.f, 0.f, 0.f);
    if (n0 + row < NN) v = *(const float4*)(x + (size_t)(n0 + row) * CC + kc4 * 4);
    short4 sv;
    sv.x = f2bf(v.x); sv.y = f2bf(v.y); sv.z = f2bf(v.z); sv.w = f2bf(v.w);
    *(short4*)(lsA + row * LSTR + kc4 * 4) = sv;
  }
  __syncthreads();

  const int wave = t >> 6, lane = t & 63;
  const int quad = lane >> 4, m = lane & 15;

  f32x4 acc[8];
#pragma unroll
  for (int nt = 0; nt < 8; ++nt) acc[nt] = (f32x4){0.f, 0.f, 0.f, 0.f};

#pragma unroll
  for (int kb = 0; kb < 4; ++kb) {
    const bf16x8 a =
        *(const bf16x8*)(lsA + (wave * 16 + m) * LSTR + kb * 32 + quad * 8);
#pragma unroll
    for (int nt = 0; nt < 8; ++nt) {
      bf16x8 bb = *(const bf16x8*)(Wsw + (size_t)(((nt * 4 + kb) * 64 + lane) * 8));
      acc[nt] = __builtin_amdgcn_mfma_f32_16x16x32_bf16(a, bb, acc[nt], 0, 0, 0);
    }
  }

  const float4 b0 = *(const float4*)(scsh + 2 * CC + m * 8);
  const float4 b1 = *(const float4*)(scsh + 2 * CC + m * 8 + 4);
  const float bv[8] = {b0.x, b0.y, b0.z, b0.w, b1.x, b1.y, b1.z, b1.w};

  __syncthreads();  // all A-tile reads done; reuse lsA for the output tile

  // stage bf16 output tile [64][LSTR]: lane m holds natural cols m*8..+7
#pragma unroll
  for (int reg = 0; reg < 4; ++reg) {
    const int r = wave * 16 + quad * 4 + reg;  // local row 0..63
    bf16x8 hv;
#pragma unroll
    for (int nt = 0; nt < 8; ++nt) hv[nt] = f2bf(acc[nt][reg] + bv[nt]);
    *(bf16x8*)(lsA + r * LSTR + m * 8) = hv;
  }
  __syncthreads();

  // copy out: per group g, rows of 16 bf16 are contiguous in h[g][node][16]
  // -> 2KB contiguous runs. 2 groups per round, 128 threads per group.
#pragma unroll
  for (int rr = 0; rr < 4; ++rr) {
    const int g2 = rr * 2 + (t >> 7);
    const int idx = t & 127;
    const int row = idx >> 1, half = idx & 1;
    const int R = n0 + row;
    if (R < NN) {
      bf16x8 v = *(const bf16x8*)(lsA + row * LSTR + g2 * 16 + half * 8);
      *(bf16x8*)(hout + (size_t)g2 * (NN * 16) + (size_t)R * 16 + half * 8) = v;
    }
  }
}

// ---------------------------------------------------------------------------
// K3: one 1024-thread block per bucket. segbase from LDS scan of bhist;
// per-dst histogram + scan -> off[]; scatter srcs into LDS csr segment;
// coalesced copy-out.
// ---------------------------------------------------------------------------
__global__ __launch_bounds__(1024) void bucket_to_csr(
    const int2* __restrict__ ebuf, const int* __restrict__ bhist,
    int* __restrict__ off, int* __restrict__ csr) {
  __shared__ int gs[NBUK];
  __shared__ int dh[512];
  __shared__ int s[512];
  __shared__ int lcur[512];
  __shared__ int lcsr[CAP];  // 40 KB
  const int b = blockIdx.x, t = threadIdx.x;

  if (t < NBUK) gs[t] = bhist[t];
  __syncthreads();
  for (int d = 1; d < NBUK; d <<= 1) {
    int a0 = 0;
    if (t < NBUK && t >= d) a0 = gs[t - d];
    __syncthreads();
    if (t < NBUK) gs[t] += a0;
    __syncthreads();
  }
  const int seglen = bhist[b];
  const int segbase = gs[b] - seglen;
  const int lo = b * DPB;
  const int hi = min(NN, lo + DPB);
  const int nd = hi - lo;
  const int2* eb = ebuf + segbase;

  if (t < 512) dh[t] = 0;
  __syncthreads();
  for (int i = t; i < seglen; i += 1024) atomicAdd(&dh[eb[i].y - lo], 1);
  __syncthreads();

  if (t < 512) s[t] = dh[t];
  __syncthreads();
  for (int d = 1; d < 512; d <<= 1) {
    int a0 = 0;
    if (t < 512 && t >= d) a0 = s[t - d];
    __syncthreads();
    if (t < 512) s[t] += a0;
    __syncthreads();
  }
  if (t < 512) lcur[t] = s[t] - dh[t];  // exclusive
  if (t < nd) off[lo + t] = segbase + (s[t] - dh[t]);
  if (b == NBUK - 1 && t == 0) off[NN] = NE;
  __syncthreads();

  if (seglen <= CAP) {
    for (int i = t; i < seglen; i += 1024) {
      const int2 e = eb[i];
      const int p = atomicAdd(&lcur[e.y - lo], 1);
      lcsr[p] = e.x;
    }
    __syncthreads();
    for (int i = t; i < seglen; i += 1024) csr[segbase + i] = lcsr[i];
  } else {
    for (int i = t; i < seglen; i += 1024) {
      const int2 e = eb[i];
      const int p = atomicAdd(&lcur[e.y - lo], 1);
      csr[segbase + p] = e.x;
    }
  }
}

// ---------------------------------------------------------------------------
// K4: 8-edge-parallel sliced gather. g = bid&7 -> column group == XCD (h
// slice 3.2MB L2-resident). Block covers GNB=256 nodes; csr segment staged
// to LDS (contiguous, dst-sorted). Each wave processes ONE node at a time
// (64 nodes serial): lane = (e = lane&7, c = lane>>3); per iteration one
// VMEM instr covers 8 edges x 32B; reduce over e via __shfl_xor 1/2/4
// (32-lane-local); lanes e==0 do BN+ReLU and store float2 (contig 64B).
// ---------------------------------------------------------------------------
__global__ __launch_bounds__(256) void gather_bn_relu(
    const short* __restrict__ h, const int* __restrict__ off,
    const int* __restrict__ csr, const float* __restrict__ scsh,
    float* __restrict__ out) {
  __shared__ int loff[GNB + 1];
  __shared__ int lcsr[CAP2];  // 20 KB
  const int g = blockIdx.x & 7;
  const int nb0 = (blockIdx.x >> 3) * GNB;
  const int t = threadIdx.x;
  const int nnb = min(GNB, NN - nb0);

  for (int i = t; i <= nnb; i += 256) loff[i] = off[nb0 + i];
  __syncthreads();
  const int s0 = loff[0];
  const int seglen = loff[nnb] - s0;
  const int stg = min(seglen, CAP2);
  for (int i = t; i < stg; i += 256) lcsr[i] = csr[s0 + i];
  __syncthreads();

  const int wave = t >> 6, lane = t & 63;
  const int el = lane & 7;        // edge sub-lane
  const int c8 = lane >> 3;       // uint column (2 natural cols)
  const unsigned* hb = (const unsigned*)(h + (size_t)g * (NN * 16)) + c8;
  const float2 sc = *(const float2*)(scsh + g * 16 + c8 * 2);
  const float2 sh = *(const float2*)(scsh + CC + g * 16 + c8 * 2);

  const int lEnd = min(nnb, wave * 64 + 64);
  if (seglen <= CAP2) {
    for (int l = wave * 64; l < lEnd; ++l) {
      const int s = loff[l] - s0, en = loff[l + 1] - s0;
      float ax = 0.f, ay = 0.f;
      int i = s + el;
      for (; i + 8 < en; i += 16) {
        const int q0 = lcsr[i], q1 = lcsr[i + 8];
        const unsigned p0 = hb[(size_t)q0 * 8];
        const unsigned p1 = hb[(size_t)q1 * 8];
        ax += bflo(p0) + bflo(p1);
        ay += bfhi(p0) + bfhi(p1);
      }
      if (i < en) {
        const unsigned p = hb[(size_t)lcsr[i] * 8];
        ax += bflo(p); ay += bfhi(p);
      }
      ax += __shfl_xor(ax, 1); ay += __shfl_xor(ay, 1);
      ax += __shfl_xor(ax, 2); ay += __shfl_xor(ay, 2);
      ax += __shfl_xor(ax, 4); ay += __shfl_xor(ay, 4);
      if (el == 0) {
        const float inv = (en > s) ? 1.0f / (float)(en - s) : 0.0f;
        float2 o;
        o.x = fmaxf(0.f, ax * inv * sc.x + sh.x);
        o.y = fmaxf(0.f, ay * inv * sc.y + sh.y);
        *(float2*)(out + (size_t)(nb0 + l) * CC + g * 16 + c8 * 2) = o;
      }
    }
  } else {
    // rare (> mean+16sigma): csr straight from global
    for (int l = wave * 64; l < lEnd; ++l) {
      const int s = loff[l], en = loff[l + 1];
      float ax = 0.f, ay = 0.f;
      int i = s + el;
      for (; i + 8 < en; i += 16) {
        const int q0 = csr[i], q1 = csr[i + 8];
        const unsigned p0 = hb[(size_t)q0 * 8];
        const unsigned p1 = hb[(size_t)q1 * 8];
        ax += bflo(p0) + bflo(p1);
        ay += bfhi(p0) + bfhi(p1);
      }
      if (i < en) {
        const unsigned p = hb[(size_t)csr[i] * 8];
        ax += bflo(p); ay += bfhi(p);
      }
      ax += __shfl_xor(ax, 1); ay += __shfl_xor(ay, 1);
      ax += __shfl_xor(ax, 2); ay += __shfl_xor(ay, 2);
      ax += __shfl_xor(ax, 4); ay += __shfl_xor(ay, 4);
      if (el == 0) {
        const float inv = (en > s) ? 1.0f / (float)(en - s) : 0.0f;
        float2 o;
        o.x = fmaxf(0.f, ax * inv * sc.x + sh.x);
        o.y = fmaxf(0.f, ay * inv * sc.y + sh.y);
        *(float2*)(out + (size_t)(nb0 + l) * CC + g * 16 + c8 * 2) = o;
      }
    }
  }
}

// ---------------------------------------------------------------------------
// Fallback (small ws): atomic scatter + fp32 vector GEMM.
// ---------------------------------------------------------------------------
__global__ __launch_bounds__(256) void edge_scatter(
    const float* __restrict__ x, const int* __restrict__ ei,
    float* __restrict__ sums, int* __restrict__ cnt) {
  int gt = blockIdx.x * 256 + threadIdx.x;
  int e = gt >> 5;
  int sub = gt & 31;
  if (e >= NE) return;
  int src = ei[e];
  int dst = ei[NE + e];
  const float4 v = *(const float4*)(x + (size_t)src * CC + sub * 4);
  float* o = sums + (size_t)dst * CC + sub * 4;
  unsafeAtomicAdd(o + 0, v.x);
  unsafeAtomicAdd(o + 1, v.y);
  unsafeAtomicAdd(o + 2, v.z);
  unsafeAtomicAdd(o + 3, v.w);
  if (sub == 0) atomicAdd(cnt + dst, 1);
}

__global__ __launch_bounds__(256) void gemm_bn_relu_fb(
    float* buf, const float* __restrict__ W, const float* __restrict__ bias,
    const float* __restrict__ gamma, const float* __restrict__ beta,
    const float* __restrict__ rmean, const float* __restrict__ rvar,
    const int* __restrict__ cnt) {
  __shared__ float xsT[CC][65];
  const int t = threadIdx.x;
  const int n0 = blockIdx.x * 64;
  for (int j = 0; j < 8; ++j) {
    int i = t + 256 * j;
    int row = i >> 5;
    int ko = (i & 31) * 4;
    float4 v = make_float4(0.f, 0.f, 0.f, 0.f);
    if (n0 + row < NN) v = *(const float4*)(buf + (size_t)(n0 + row) * CC + ko);
    xsT[ko + 0][row] = v.x;
    xsT[ko + 1][row] = v.y;
    xsT[ko + 2][row] = v.z;
    xsT[ko + 3][row] = v.w;
  }
  __syncthreads();
  const int cg = t & 31;
  const int ng8 = (t >> 5) * 8;
  float acc[8][4];
#pragma unroll
  for (int j = 0; j < 8; ++j)
#pragma unroll
    for (int c = 0; c < 4; ++c) acc[j][c] = 0.f;
#pragma unroll 8
  for (int k = 0; k < CC; ++k) {
    const float4 wv = *(const float4*)(W + k * CC + cg * 4);
#pragma unroll
    for (int j = 0; j < 8; ++j) {
      const float xv = xsT[k][ng8 + j];
      acc[j][0] = fmaf(xv, wv.x, acc[j][0]);
      acc[j][1] = fmaf(xv, wv.y, acc[j][1]);
      acc[j][2] = fmaf(xv, wv.z, acc[j][2]);
      acc[j][3] = fmaf(xv, wv.w, acc[j][3]);
    }
  }
  const float4 bb = *(const float4*)(bias + cg * 4);
  const float4 gg = *(const float4*)(gamma + cg * 4);
  const float4 bt = *(const float4*)(beta + cg * 4);
  const float4 mu = *(const float4*)(rmean + cg * 4);
  const float4 vr = *(const float4*)(rvar + cg * 4);
  float sc[4], sh[4];
  sc[0] = gg.x * rsqrtf(vr.x + BN_EPS);
  sc[1] = gg.y * rsqrtf(vr.y + BN_EPS);
  sc[2] = gg.z * rsqrtf(vr.z + BN_EPS);
  sc[3] = gg.w * rsqrtf(vr.w + BN_EPS);
  sh[0] = bt.x - mu.x * sc[0];
  sh[1] = bt.y - mu.y * sc[1];
  sh[2] = bt.z - mu.z * sc[2];
  sh[3] = bt.w - mu.w * sc[3];
#pragma unroll
  for (int j = 0; j < 8; ++j) {
    const int n = n0 + ng8 + j;
    if (n >= NN) continue;
    const int cn = cnt[n];
    const float inv = cn > 0 ? 1.0f / (float)cn : 0.0f;
    const float bsel = cn > 0 ? 1.0f : 0.0f;
    float4 o;
    o.x = fmaxf(0.f, (acc[j][0] * inv + bsel * bb.x) * sc[0] + sh[0]);
    o.y = fmaxf(0.f, (acc[j][1] * inv + bsel * bb.y) * sc[1] + sh[1]);
    o.z = fmaxf(0.f, (acc[j][2] * inv + bsel * bb.z) * sc[2] + sh[2]);
    o.w = fmaxf(0.f, (acc[j][3] * inv + bsel * bb.w) * sc[3] + sh[3]);
    *(float4*)(buf + (size_t)n * CC + cg * 4) = o;
  }
}

extern "C" void kernel_launch(void* const* d_in, const int* in_sizes, int n_in,
                              void* d_out, int out_size, void* d_ws, size_t ws_size,
                              hipStream_t stream) {
  const float* x     = (const float*)d_in[0];
  const int*   ei    = (const int*)d_in[1];
  const float* W     = (const float*)d_in[2];
  const float* bias  = (const float*)d_in[3];
  const float* gamma = (const float*)d_in[4];
  const float* beta  = (const float*)d_in[5];
  const float* rmean = (const float*)d_in[6];
  const float* rvar  = (const float*)d_in[7];
  float* out = (float*)d_out;

  // ws layout (bytes):
  //   off[NN+1] | bhist[256] | gcurz[256] (contiguous -> one 2KB memset)
  //   | csr[NE] | scsh[384f] | Wsw[16384 bf16] | ebuf int2[NE] | h[NN*CC bf16]
  const size_t OFF_B  = 0;
  const size_t BH_B   = 400128;
  const size_t GC_B   = 401152;
  const size_t CSR_B  = 802304;
  const size_t SCSH_B = 7202304;
  const size_t WSW_B  = 7204352;
  const size_t EB_B   = 7237120;
  const size_t H1_B   = 20037120;                     // tier-1 h (after ebuf)
  const size_t NEED1  = H1_B + (size_t)NN * CC * 2;   // 45,637,120
  const size_t NEED2  = EB_B + (size_t)NN * CC * 2;   // 32,837,120 (alias)

  const int GGRID = ((NN + GNB - 1) / GNB) * 8;  // 391 node-blocks x 8 groups

  if (ws_size >= NEED2) {
    int*   off   = (int*)((char*)d_ws + OFF_B);
    int*   bhist = (int*)((char*)d_ws + BH_B);
    int*   gcurz = (int*)((char*)d_ws + GC_B);
    int*   csr   = (int*)((char*)d_ws + CSR_B);
    float* scsh  = (float*)((char*)d_ws + SCSH_B);
    short* Wsw   = (short*)((char*)d_ws + WSW_B);

    hipMemsetAsync(bhist, 0, 2048, stream);  // bhist + gcurz
    prep_hist<<<ABLK, 256, 0, stream>>>(W, bias, gamma, beta, rmean, rvar,
                                        ei, Wsw, scsh, bhist);
    if (ws_size >= NEED1) {
      // tier 1: fused scatter+linear (ebuf and h distinct)
      int2*  ebuf = (int2*)((char*)d_ws + EB_B);
      short* h    = (short*)((char*)d_ws + H1_B);
      scatter_linear<<<ABLK + LBLK, 256, 0, stream>>>(
          ei, bhist, gcurz, ebuf, x, Wsw, scsh, h, ABLK);
      bucket_to_csr<<<NBUK, 1024, 0, stream>>>(ebuf, bhist, off, csr);
      gather_bn_relu<<<GGRID, 256, 0, stream>>>(h, off, csr, scsh, out);
    } else {
      // tier 2: un-fused, ebuf aliases h (r8-proven ordering)
      int2*  ebuf = (int2*)((char*)d_ws + EB_B);
      short* h    = (short*)((char*)d_ws + EB_B);
      scatter_linear<<<ABLK, 256, 0, stream>>>(
          ei, bhist, gcurz, ebuf, x, Wsw, scsh, h, ABLK);  // scatter only
      bucket_to_csr<<<NBUK, 1024, 0, stream>>>(ebuf, bhist, off, csr);
      scatter_linear<<<LBLK, 256, 0, stream>>>(
          ei, bhist, gcurz, ebuf, x, Wsw, scsh, h, 0);     // linear only
      gather_bn_relu<<<GGRID, 256, 0, stream>>>(h, off, csr, scsh, out);
    }
  } else {
    int* cnt = (int*)d_ws;
    hipMemsetAsync(out, 0, (size_t)NN * CC * sizeof(float), stream);
    hipMemsetAsync(cnt, 0, (size_t)NN * sizeof(int), stream);
    edge_scatter<<<(NE * 32) / 256, 256, 0, stream>>>(x, ei, out, cnt);
    gemm_bn_relu_fb<<<(NN + 63) / 64, 256, 0, stream>>>(
        out, W, bias, gamma, beta, rmean, rvar, cnt);
  }
}

// Round 6
// 237.583 us; speedup vs baseline: 5.0039x; 1.2496x over previous
//
#include <hip/hip_runtime.h>

// GCN layer on MI355X — round 15: octet + LDS-csr sliced gather.
// History: r8 full-row 71.7us | r10 sliced 8x-waves 227.9 | r11 octet 98.6
// (csr VMEM + latency) | r12 LDS-csr serial-node 80.5 (divergence) | r13 LDS
// atomics 1049 (dead end) | r14 8-edge-parallel 146.8 (30M instrs: 20M was
// per-node-group epilogue/shuffles).  This round: wave = 8 nodes x 8 cols
// CONCURRENT (epilogue amortized 8-wide, zero shuffles) + csr staged in LDS
// (octet lanes broadcast-read same word; h loads keep 8 edge-visits/VMEM).
//   M1:  memsetAsync(bhist+gcurz, 0, 2KB)
//   K1 prep_hist:      Wsw swizzle + BN consts FUSED with bucket histogram
//   K2 scatter_linear: bucket_scatter (391) FUSED with linear_mfma (1563);
//                      h GROUP-MAJOR [8][NN][16] bf16, LDS-staged stores.
//   K3 bucket_to_csr:  1024 threads/block.
//   K4 gather_bn_relu: block = 256 nodes x group g (g=bid&7 -> XCD; slice
//                      3.2MB L2-resident, PROVEN FETCH 179->60MB). Wave
//                      processes 64 nodes as 8 rounds x 8 concurrent nodes;
//                      lane=(o=lane>>3 node, c8=lane&7 uint-col); 4-deep
//                      unroll; csr via LDS broadcast; no cross-lane reduce.
// mean(h[src]) = mean(x[src])@W + b (linearity); deg=0 -> sum=0 -> relu(sh).

#define NN 100000
#define NE 1600000
#define CC 128
#define BN_EPS 1e-5f
#define LBLK 1563     // ceil(NN/64) linear blocks
#define LSTR 136      // LDS row stride in bf16 (128 + 8 pad)
#define NBUK 256      // dst buckets
#define DPB 391       // dsts per bucket (256*391 = 100096 >= NN)
#define ACH 4096      // edges per scatter block
#define ABLK 391      // ceil(NE/ACH)
#define CAP 10240     // to_csr LDS segment capacity (mean 6250, huge margin)
#define GNB 256       // nodes per gather block
#define CAP2 5120     // gather csr LDS capacity (mean 4096, sd 64: +16sigma)

typedef __attribute__((ext_vector_type(8))) short bf16x8;
typedef __attribute__((ext_vector_type(4))) float f32x4;

static __device__ __forceinline__ short f2bf(float f) {
  union { float f; unsigned u; } v; v.f = f;
  unsigned r = (v.u + 0x7FFF + ((v.u >> 16) & 1)) >> 16;  // RNE
  return (short)r;
}
static __device__ __forceinline__ float bflo(unsigned p) {
  return __uint_as_float(p << 16);
}
static __device__ __forceinline__ float bfhi(unsigned p) {
  return __uint_as_float(p & 0xffff0000u);
}

// 256-wide Hillis-Steele scan in LDS; leaves a[] exclusive, returns excl[t].
// (256-thread blocks only.)
static __device__ __forceinline__ int excl_scan256(int* a, int t, int v) {
  a[t] = v;
  __syncthreads();
  for (int d = 1; d < 256; d <<= 1) {
    const int x = (t >= d) ? a[t - d] : 0;
    __syncthreads();
    a[t] += x;
    __syncthreads();
  }
  const int incl = a[t];
  __syncthreads();
  a[t] = incl - v;
  __syncthreads();
  return incl - v;
}

// ---------------------------------------------------------------------------
// K1: prep (Wsw swizzle, col-permuted so D-lane m holds natural cols m*8..+7;
// BN scale/shift + bias) on blocks 0-63, bucket histogram on all 391 blocks.
// bhist pre-zeroed by the M1 memset.
// ---------------------------------------------------------------------------
__global__ __launch_bounds__(256) void prep_hist(
    const float* __restrict__ W, const float* __restrict__ bias,
    const float* __restrict__ gamma, const float* __restrict__ beta,
    const float* __restrict__ rmean, const float* __restrict__ rvar,
    const int* __restrict__ ei, short* __restrict__ Wsw,
    float* __restrict__ scsh, int* __restrict__ bhist) {
  __shared__ int lh[NBUK];
  const int t = threadIdx.x;
  const int i = blockIdx.x * 256 + t;
  if (i < CC * CC) {
    const int k = i >> 7, n = i & 127;
    const int nt = n & 7, m = n >> 3;
    const int kb = k >> 5, q = (k >> 3) & 3, j = k & 7;
    Wsw[(size_t)(((nt * 4 + kb) * 64 + (m + 16 * q)) * 8 + j)] = f2bf(W[i]);
  }
  if (i < CC) {
    const float sc = gamma[i] * rsqrtf(rvar[i] + BN_EPS);
    scsh[i] = sc;
    scsh[CC + i] = beta[i] - rmean[i] * sc;
    scsh[2 * CC + i] = bias[i];
  }
  lh[t] = 0;
  __syncthreads();
  const int e0 = blockIdx.x * ACH;
  const int e1 = min(NE, e0 + ACH);
  for (int e = e0 + t; e < e1; e += 256) atomicAdd(&lh[ei[NE + e] / DPB], 1);
  __syncthreads();
  if (lh[t]) atomicAdd(&bhist[t], lh[t]);
}

// ---------------------------------------------------------------------------
// K2: blocks [0,scat): bucket_scatter — chunk-sort 4096 edges by bucket in
// LDS, reserve contiguous global runs, write ebuf coalesced. blocks
// [scat,..): linear_mfma — h = bf16(x@W+b), LDS-staged input, MFMA, then
// output tile re-staged in LDS and stored as per-group contiguous runs.
// ---------------------------------------------------------------------------
__global__ __launch_bounds__(256) void scatter_linear(
    const int* __restrict__ ei, const int* __restrict__ bhist,
    int* __restrict__ gcurz, int2* __restrict__ ebuf,
    const float* __restrict__ x, const short* __restrict__ Wsw,
    const float* __restrict__ scsh, short* __restrict__ hout,
    int scat) {
  __shared__ int2 sorted[ACH];  // 32 KB (linear role aliases as bf16 tile)
  __shared__ int gsc[NBUK], lh[NBUK], lex[NBUK], rb[NBUK], lc[NBUK];
  const int t = threadIdx.x;

  if (blockIdx.x < scat) {
    // ----- scatter role -----
    const int e0 = blockIdx.x * ACH;
    const int e1 = min(NE, e0 + ACH);
    const int gbase = excl_scan256(gsc, t, bhist[t]);
    lh[t] = 0;
    __syncthreads();
    for (int e = e0 + t; e < e1; e += 256) atomicAdd(&lh[ei[NE + e] / DPB], 1);
    __syncthreads();
    const int vh = lh[t];
    const int lbase = excl_scan256(lex, t, vh);
    lc[t] = lbase;
    if (vh > 0) rb[t] = gbase + atomicAdd(&gcurz[t], vh);
    __syncthreads();
    for (int e = e0 + t; e < e1; e += 256) {
      const int src = ei[e], dst = ei[NE + e];
      const int p = atomicAdd(&lc[dst / DPB], 1);
      sorted[p] = make_int2(src, dst);
    }
    __syncthreads();
    const int n = e1 - e0;
    for (int i = t; i < n; i += 256) {
      const int2 v = sorted[i];
      const int b = v.y / DPB;
      ebuf[rb[b] + (i - lex[b])] = v;
    }
    return;
  }

  // ----- linear role -----
  short* lsA = (short*)sorted;  // 64*LSTR*2 = 17.4 KB <= 32 KB
  const int n0 = (blockIdx.x - scat) * 64;

#pragma unroll
  for (int j = 0; j < 8; ++j) {
    const int idx = j * 256 + t;
    const int row = idx >> 5, kc4 = idx & 31;
    float4 v = make_float4(0.f, 0.f, 0.f, 0.f);
    if (n0 + row < NN) v = *(const float4*)(x + (size_t)(n0 + row) * CC + kc4 * 4);
    short4 sv;
    sv.x = f2bf(v.x); sv.y = f2bf(v.y); sv.z = f2bf(v.z); sv.w = f2bf(v.w);
    *(short4*)(lsA + row * LSTR + kc4 * 4) = sv;
  }
  __syncthreads();

  const int wave = t >> 6, lane = t & 63;
  const int quad = lane >> 4, m = lane & 15;

  f32x4 acc[8];
#pragma unroll
  for (int nt = 0; nt < 8; ++nt) acc[nt] = (f32x4){0.f, 0.f, 0.f, 0.f};

#pragma unroll
  for (int kb = 0; kb < 4; ++kb) {
    const bf16x8 a =
        *(const bf16x8*)(lsA + (wave * 16 + m) * LSTR + kb * 32 + quad * 8);
#pragma unroll
    for (int nt = 0; nt < 8; ++nt) {
      bf16x8 bb = *(const bf16x8*)(Wsw + (size_t)(((nt * 4 + kb) * 64 + lane) * 8));
      acc[nt] = __builtin_amdgcn_mfma_f32_16x16x32_bf16(a, bb, acc[nt], 0, 0, 0);
    }
  }

  const float4 b0 = *(const float4*)(scsh + 2 * CC + m * 8);
  const float4 b1 = *(const float4*)(scsh + 2 * CC + m * 8 + 4);
  const float bv[8] = {b0.x, b0.y, b0.z, b0.w, b1.x, b1.y, b1.z, b1.w};

  __syncthreads();  // all A-tile reads done; reuse lsA for the output tile

  // stage bf16 output tile [64][LSTR]: lane m holds natural cols m*8..+7
#pragma unroll
  for (int reg = 0; reg < 4; ++reg) {
    const int r = wave * 16 + quad * 4 + reg;  // local row 0..63
    bf16x8 hv;
#pragma unroll
    for (int nt = 0; nt < 8; ++nt) hv[nt] = f2bf(acc[nt][reg] + bv[nt]);
    *(bf16x8*)(lsA + r * LSTR + m * 8) = hv;
  }
  __syncthreads();

  // copy out: per group g, rows of 16 bf16 are contiguous in h[g][node][16]
  // -> 2KB contiguous runs. 2 groups per round, 128 threads per group.
#pragma unroll
  for (int rr = 0; rr < 4; ++rr) {
    const int g2 = rr * 2 + (t >> 7);
    const int idx = t & 127;
    const int row = idx >> 1, half = idx & 1;
    const int R = n0 + row;
    if (R < NN) {
      bf16x8 v = *(const bf16x8*)(lsA + row * LSTR + g2 * 16 + half * 8);
      *(bf16x8*)(hout + (size_t)g2 * (NN * 16) + (size_t)R * 16 + half * 8) = v;
    }
  }
}

// ---------------------------------------------------------------------------
// K3: one 1024-thread block per bucket. segbase from LDS scan of bhist;
// per-dst histogram + scan -> off[]; scatter srcs into LDS csr segment;
// coalesced copy-out.
// ---------------------------------------------------------------------------
__global__ __launch_bounds__(1024) void bucket_to_csr(
    const int2* __restrict__ ebuf, const int* __restrict__ bhist,
    int* __restrict__ off, int* __restrict__ csr) {
  __shared__ int gs[NBUK];
  __shared__ int dh[512];
  __shared__ int s[512];
  __shared__ int lcur[512];
  __shared__ int lcsr[CAP];  // 40 KB
  const int b = blockIdx.x, t = threadIdx.x;

  if (t < NBUK) gs[t] = bhist[t];
  __syncthreads();
  for (int d = 1; d < NBUK; d <<= 1) {
    int a0 = 0;
    if (t < NBUK && t >= d) a0 = gs[t - d];
    __syncthreads();
    if (t < NBUK) gs[t] += a0;
    __syncthreads();
  }
  const int seglen = bhist[b];
  const int segbase = gs[b] - seglen;
  const int lo = b * DPB;
  const int hi = min(NN, lo + DPB);
  const int nd = hi - lo;
  const int2* eb = ebuf + segbase;

  if (t < 512) dh[t] = 0;
  __syncthreads();
  for (int i = t; i < seglen; i += 1024) atomicAdd(&dh[eb[i].y - lo], 1);
  __syncthreads();

  if (t < 512) s[t] = dh[t];
  __syncthreads();
  for (int d = 1; d < 512; d <<= 1) {
    int a0 = 0;
    if (t < 512 && t >= d) a0 = s[t - d];
    __syncthreads();
    if (t < 512) s[t] += a0;
    __syncthreads();
  }
  if (t < 512) lcur[t] = s[t] - dh[t];  // exclusive
  if (t < nd) off[lo + t] = segbase + (s[t] - dh[t]);
  if (b == NBUK - 1 && t == 0) off[NN] = NE;
  __syncthreads();

  if (seglen <= CAP) {
    for (int i = t; i < seglen; i += 1024) {
      const int2 e = eb[i];
      const int p = atomicAdd(&lcur[e.y - lo], 1);
      lcsr[p] = e.x;
    }
    __syncthreads();
    for (int i = t; i < seglen; i += 1024) csr[segbase + i] = lcsr[i];
  } else {
    for (int i = t; i < seglen; i += 1024) {
      const int2 e = eb[i];
      const int p = atomicAdd(&lcur[e.y - lo], 1);
      csr[segbase + p] = e.x;
    }
  }
}

// ---------------------------------------------------------------------------
// K4: octet + LDS-csr sliced gather. g = bid&7 -> column group == XCD (slice
// 3.2MB L2-resident). Block = 256 nodes; loff + csr segment staged in LDS.
// Wave: 8 rounds x 8 concurrent nodes; lane = (o = lane>>3 -> node,
// c8 = lane&7 -> uint col). Octet lanes broadcast-read the same lcsr word
// (conflict-free); one 4B h load per edge per lane (8 edge-visits / VMEM
// instr); 4-deep unroll; NO cross-lane reduce, epilogue amortized 8-wide.
// ---------------------------------------------------------------------------
__global__ __launch_bounds__(256) void gather_bn_relu(
    const short* __restrict__ h, const int* __restrict__ off,
    const int* __restrict__ csr, const float* __restrict__ scsh,
    float* __restrict__ out) {
  __shared__ int loff[GNB + 1];
  __shared__ int lcsr[CAP2];  // 20 KB
  const int g = blockIdx.x & 7;
  const int nb0 = (blockIdx.x >> 3) * GNB;
  const int t = threadIdx.x;
  const int nnb = min(GNB, NN - nb0);

  for (int i = t; i <= nnb; i += 256) loff[i] = off[nb0 + i];
  __syncthreads();
  const int s0 = loff[0];
  const int seglen = loff[nnb] - s0;
  const int stg = min(seglen, CAP2);
  for (int i = t; i < stg; i += 256) lcsr[i] = csr[s0 + i];
  __syncthreads();

  const int wave = t >> 6, lane = t & 63;
  const int o = lane >> 3;   // node sub-lane (8 concurrent nodes)
  const int c8 = lane & 7;   // uint column (2 natural cols)
  const unsigned* hb = (const unsigned*)h + (size_t)g * (NN * 8) + c8;
  const float2 sc = *(const float2*)(scsh + g * 16 + c8 * 2);
  const float2 sh = *(const float2*)(scsh + CC + g * 16 + c8 * 2);

  if (seglen <= CAP2) {
#pragma unroll
    for (int r = 0; r < 8; ++r) {
      const int l = wave * 64 + r * 8 + o;
      int s = 0, e = 0;
      if (l < nnb) { s = loff[l] - s0; e = loff[l + 1] - s0; }
      float ax = 0.f, ay = 0.f;
      int i = s;
      for (; i + 4 <= e; i += 4) {
        const int q0 = lcsr[i], q1 = lcsr[i + 1];
        const int q2 = lcsr[i + 2], q3 = lcsr[i + 3];
        const unsigned p0 = hb[(size_t)q0 * 8];
        const unsigned p1 = hb[(size_t)q1 * 8];
        const unsigned p2 = hb[(size_t)q2 * 8];
        const unsigned p3 = hb[(size_t)q3 * 8];
        ax += (bflo(p0) + bflo(p1)) + (bflo(p2) + bflo(p3));
        ay += (bfhi(p0) + bfhi(p1)) + (bfhi(p2) + bfhi(p3));
      }
      for (; i < e; ++i) {
        const unsigned p = hb[(size_t)lcsr[i] * 8];
        ax += bflo(p); ay += bfhi(p);
      }
      if (l < nnb) {
        const float inv = (e > s) ? 1.0f / (float)(e - s) : 0.0f;
        float2 o2;
        o2.x = fmaxf(0.f, ax * inv * sc.x + sh.x);
        o2.y = fmaxf(0.f, ay * inv * sc.y + sh.y);
        *(float2*)(out + (size_t)(nb0 + l) * CC + g * 16 + c8 * 2) = o2;
      }
    }
  } else {
    // rare (> mean+16sigma): csr straight from global
#pragma unroll
    for (int r = 0; r < 8; ++r) {
      const int l = wave * 64 + r * 8 + o;
      int s = 0, e = 0;
      if (l < nnb) { s = loff[l]; e = loff[l + 1]; }
      float ax = 0.f, ay = 0.f;
      int i = s;
      for (; i + 4 <= e; i += 4) {
        const int q0 = csr[i], q1 = csr[i + 1];
        const int q2 = csr[i + 2], q3 = csr[i + 3];
        const unsigned p0 = hb[(size_t)q0 * 8];
        const unsigned p1 = hb[(size_t)q1 * 8];
        const unsigned p2 = hb[(size_t)q2 * 8];
        const unsigned p3 = hb[(size_t)q3 * 8];
        ax += (bflo(p0) + bflo(p1)) + (bflo(p2) + bflo(p3));
        ay += (bfhi(p0) + bfhi(p1)) + (bfhi(p2) + bfhi(p3));
      }
      for (; i < e; ++i) {
        const unsigned p = hb[(size_t)csr[i] * 8];
        ax += bflo(p); ay += bfhi(p);
      }
      if (l < nnb) {
        const float inv = (e > s) ? 1.0f / (float)(e - s) : 0.0f;
        float2 o2;
        o2.x = fmaxf(0.f, ax * inv * sc.x + sh.x);
        o2.y = fmaxf(0.f, ay * inv * sc.y + sh.y);
        *(float2*)(out + (size_t)(nb0 + l) * CC + g * 16 + c8 * 2) = o2;
      }
    }
  }
}

// ---------------------------------------------------------------------------
// Fallback (small ws): atomic scatter + fp32 vector GEMM.
// ---------------------------------------------------------------------------
__global__ __launch_bounds__(256) void edge_scatter(
    const float* __restrict__ x, const int* __restrict__ ei,
    float* __restrict__ sums, int* __restrict__ cnt) {
  int gt = blockIdx.x * 256 + threadIdx.x;
  int e = gt >> 5;
  int sub = gt & 31;
  if (e >= NE) return;
  int src = ei[e];
  int dst = ei[NE + e];
  const float4 v = *(const float4*)(x + (size_t)src * CC + sub * 4);
  float* o = sums + (size_t)dst * CC + sub * 4;
  unsafeAtomicAdd(o + 0, v.x);
  unsafeAtomicAdd(o + 1, v.y);
  unsafeAtomicAdd(o + 2, v.z);
  unsafeAtomicAdd(o + 3, v.w);
  if (sub == 0) atomicAdd(cnt + dst, 1);
}

__global__ __launch_bounds__(256) void gemm_bn_relu_fb(
    float* buf, const float* __restrict__ W, const float* __restrict__ bias,
    const float* __restrict__ gamma, const float* __restrict__ beta,
    const float* __restrict__ rmean, const float* __restrict__ rvar,
    const int* __restrict__ cnt) {
  __shared__ float xsT[CC][65];
  const int t = threadIdx.x;
  const int n0 = blockIdx.x * 64;
  for (int j = 0; j < 8; ++j) {
    int i = t + 256 * j;
    int row = i >> 5;
    int ko = (i & 31) * 4;
    float4 v = make_float4(0.f, 0.f, 0.f, 0.f);
    if (n0 + row < NN) v = *(const float4*)(buf + (size_t)(n0 + row) * CC + ko);
    xsT[ko + 0][row] = v.x;
    xsT[ko + 1][row] = v.y;
    xsT[ko + 2][row] = v.z;
    xsT[ko + 3][row] = v.w;
  }
  __syncthreads();
  const int cg = t & 31;
  const int ng8 = (t >> 5) * 8;
  float acc[8][4];
#pragma unroll
  for (int j = 0; j < 8; ++j)
#pragma unroll
    for (int c = 0; c < 4; ++c) acc[j][c] = 0.f;
#pragma unroll 8
  for (int k = 0; k < CC; ++k) {
    const float4 wv = *(const float4*)(W + k * CC + cg * 4);
#pragma unroll
    for (int j = 0; j < 8; ++j) {
      const float xv = xsT[k][ng8 + j];
      acc[j][0] = fmaf(xv, wv.x, acc[j][0]);
      acc[j][1] = fmaf(xv, wv.y, acc[j][1]);
      acc[j][2] = fmaf(xv, wv.z, acc[j][2]);
      acc[j][3] = fmaf(xv, wv.w, acc[j][3]);
    }
  }
  const float4 bb = *(const float4*)(bias + cg * 4);
  const float4 gg = *(const float4*)(gamma + cg * 4);
  const float4 bt = *(const float4*)(beta + cg * 4);
  const float4 mu = *(const float4*)(rmean + cg * 4);
  const float4 vr = *(const float4*)(rvar + cg * 4);
  float sc[4], sh[4];
  sc[0] = gg.x * rsqrtf(vr.x + BN_EPS);
  sc[1] = gg.y * rsqrtf(vr.y + BN_EPS);
  sc[2] = gg.z * rsqrtf(vr.z + BN_EPS);
  sc[3] = gg.w * rsqrtf(vr.w + BN_EPS);
  sh[0] = bt.x - mu.x * sc[0];
  sh[1] = bt.y - mu.y * sc[1];
  sh[2] = bt.z - mu.z * sc[2];
  sh[3] = bt.w - mu.w * sc[3];
#pragma unroll
  for (int j = 0; j < 8; ++j) {
    const int n = n0 + ng8 + j;
    if (n >= NN) continue;
    const int cn = cnt[n];
    const float inv = cn > 0 ? 1.0f / (float)cn : 0.0f;
    const float bsel = cn > 0 ? 1.0f : 0.0f;
    float4 o;
    o.x = fmaxf(0.f, (acc[j][0] * inv + bsel * bb.x) * sc[0] + sh[0]);
    o.y = fmaxf(0.f, (acc[j][1] * inv + bsel * bb.y) * sc[1] + sh[1]);
    o.z = fmaxf(0.f, (acc[j][2] * inv + bsel * bb.z) * sc[2] + sh[2]);
    o.w = fmaxf(0.f, (acc[j][3] * inv + bsel * bb.w) * sc[3] + sh[3]);
    *(float4*)(buf + (size_t)n * CC + cg * 4) = o;
  }
}

extern "C" void kernel_launch(void* const* d_in, const int* in_sizes, int n_in,
                              void* d_out, int out_size, void* d_ws, size_t ws_size,
                              hipStream_t stream) {
  const float* x     = (const float*)d_in[0];
  const int*   ei    = (const int*)d_in[1];
  const float* W     = (const float*)d_in[2];
  const float* bias  = (const float*)d_in[3];
  const float* gamma = (const float*)d_in[4];
  const float* beta  = (const float*)d_in[5];
  const float* rmean = (const float*)d_in[6];
  const float* rvar  = (const float*)d_in[7];
  float* out = (float*)d_out;

  // ws layout (bytes):
  //   off[NN+1] | bhist[256] | gcurz[256] (contiguous -> one 2KB memset)
  //   | csr[NE] | scsh[384f] | Wsw[16384 bf16] | ebuf int2[NE] | h[NN*CC bf16]
  const size_t OFF_B  = 0;
  const size_t BH_B   = 400128;
  const size_t GC_B   = 401152;
  const size_t CSR_B  = 802304;
  const size_t SCSH_B = 7202304;
  const size_t WSW_B  = 7204352;
  const size_t EB_B   = 7237120;
  const size_t H1_B   = 20037120;                     // tier-1 h (after ebuf)
  const size_t NEED1  = H1_B + (size_t)NN * CC * 2;   // 45,637,120
  const size_t NEED2  = EB_B + (size_t)NN * CC * 2;   // 32,837,120 (alias)

  const int GGRID = ((NN + GNB - 1) / GNB) * 8;  // 391 node-blocks x 8 groups

  if (ws_size >= NEED2) {
    int*   off   = (int*)((char*)d_ws + OFF_B);
    int*   bhist = (int*)((char*)d_ws + BH_B);
    int*   gcurz = (int*)((char*)d_ws + GC_B);
    int*   csr   = (int*)((char*)d_ws + CSR_B);
    float* scsh  = (float*)((char*)d_ws + SCSH_B);
    short* Wsw   = (short*)((char*)d_ws + WSW_B);

    hipMemsetAsync(bhist, 0, 2048, stream);  // bhist + gcurz
    prep_hist<<<ABLK, 256, 0, stream>>>(W, bias, gamma, beta, rmean, rvar,
                                        ei, Wsw, scsh, bhist);
    if (ws_size >= NEED1) {
      // tier 1: fused scatter+linear (ebuf and h distinct)
      int2*  ebuf = (int2*)((char*)d_ws + EB_B);
      short* h    = (short*)((char*)d_ws + H1_B);
      scatter_linear<<<ABLK + LBLK, 256, 0, stream>>>(
          ei, bhist, gcurz, ebuf, x, Wsw, scsh, h, ABLK);
      bucket_to_csr<<<NBUK, 1024, 0, stream>>>(ebuf, bhist, off, csr);
      gather_bn_relu<<<GGRID, 256, 0, stream>>>(h, off, csr, scsh, out);
    } else {
      // tier 2: un-fused, ebuf aliases h (r8-proven ordering)
      int2*  ebuf = (int2*)((char*)d_ws + EB_B);
      short* h    = (short*)((char*)d_ws + EB_B);
      scatter_linear<<<ABLK, 256, 0, stream>>>(
          ei, bhist, gcurz, ebuf, x, Wsw, scsh, h, ABLK);  // scatter only
      bucket_to_csr<<<NBUK, 1024, 0, stream>>>(ebuf, bhist, off, csr);
      scatter_linear<<<LBLK, 256, 0, stream>>>(
          ei, bhist, gcurz, ebuf, x, Wsw, scsh, h, 0);     // linear only
      gather_bn_relu<<<GGRID, 256, 0, stream>>>(h, off, csr, scsh, out);
    }
  } else {
    int* cnt = (int*)d_ws;
    hipMemsetAsync(out, 0, (size_t)NN * CC * sizeof(float), stream);
    hipMemsetAsync(cnt, 0, (size_t)NN * sizeof(int), stream);
    edge_scatter<<<(NE * 32) / 256, 256, 0, stream>>>(x, ei, out, cnt);
    gemm_bn_relu_fb<<<(NN + 63) / 64, 256, 0, stream>>>(
        out, W, bias, gamma, beta, rmean, rvar, cnt);
  }
}

// Round 7
// 222.294 us; speedup vs baseline: 5.3480x; 1.0688x over previous
//
#include <hip/hip_runtime.h>

// GCN layer on MI355X — round 16: full-row e4xc16 dwordx4 gather.
// Gather geometry ledger: r8 full-row dword 71.7 (3.2M VMEM, ~10 VALU/edge)
// | r10 sliced 227.9 (8x waves) | r11 octet 98.6 | r12 serial-node 80.5
// (divergence) | r13 LDS-atomic 1049 | r14 edge-parallel 146.8 (epilogue x8)
// | r15 octet+LDScsr 84.1 (14M instrs). Lesson: slicing multiplies
// edge-visits or epilogues; r8's unsliced structure with 8x fewer VMEM and
// 2x fewer VALU is the remaining headroom.
//   M1:  memsetAsync(bhist+gcurz, 0, 2KB)
//   K1 prep_hist:      Wsw swizzle + BN consts FUSED with bucket histogram
//   K2 scatter_linear: bucket_scatter (391) FUSED with linear_mfma (1563);
//                      h ROW-MAJOR [NN][128] bf16, direct stores (r8-era).
//   K3 bucket_to_csr:  1024 threads/block.
//   K4 gather_bn_relu: block = 64 nodes (loff+csr staged in LDS, 6.4KB ->
//                      ~24 waves/CU). Wave = ONE node at a time (uniform
//                      trip count); lane = (e4 = lane>>4 edge slot, c16 =
//                      lane&15 col block). One dwordx4 = 4 edges x 256B
//                      full rows -> NE/4 = 0.4M h-VMEM (r8: 1.6M) + 0.4M
//                      csr ds_reads (r8: 1.6M VMEM broadcasts). ~5.3 VALU
//                      per edge (r8: ~10). Epilogue: 2-level shfl_xor
//                      (16,32) + BN on e4==0 lanes; consts hoisted.
// mean(h[src]) = mean(x[src])@W + b (linearity); deg=0 -> sum=0 -> relu(sh).

#define NN 100000
#define NE 1600000
#define CC 128
#define BN_EPS 1e-5f
#define LBLK 1563     // ceil(NN/64) linear blocks
#define LSTR 136      // LDS row stride in bf16 (128 + 8 pad)
#define NBUK 256      // dst buckets
#define DPB 391       // dsts per bucket (256*391 = 100096 >= NN)
#define ACH 4096      // edges per scatter block
#define ABLK 391      // ceil(NE/ACH)
#define CAP 10240     // to_csr LDS segment capacity (mean 6250, huge margin)
#define GNB 64        // nodes per gather block
#define CAP2 1536     // gather csr LDS cap (mean 1024, sd 32: +16sigma)

typedef __attribute__((ext_vector_type(8))) short bf16x8;
typedef __attribute__((ext_vector_type(4))) float f32x4;

static __device__ __forceinline__ short f2bf(float f) {
  union { float f; unsigned u; } v; v.f = f;
  unsigned r = (v.u + 0x7FFF + ((v.u >> 16) & 1)) >> 16;  // RNE
  return (short)r;
}
static __device__ __forceinline__ float bflo(unsigned p) {
  return __uint_as_float(p << 16);
}
static __device__ __forceinline__ float bfhi(unsigned p) {
  return __uint_as_float(p & 0xffff0000u);
}

// 256-wide Hillis-Steele scan in LDS; leaves a[] exclusive, returns excl[t].
// (256-thread blocks only.)
static __device__ __forceinline__ int excl_scan256(int* a, int t, int v) {
  a[t] = v;
  __syncthreads();
  for (int d = 1; d < 256; d <<= 1) {
    const int x = (t >= d) ? a[t - d] : 0;
    __syncthreads();
    a[t] += x;
    __syncthreads();
  }
  const int incl = a[t];
  __syncthreads();
  a[t] = incl - v;
  __syncthreads();
  return incl - v;
}

// ---------------------------------------------------------------------------
// K1: prep (Wsw swizzle, col-permuted so D-lane m holds natural cols m*8..+7;
// BN scale/shift + bias) on blocks 0-63, bucket histogram on all 391 blocks.
// bhist pre-zeroed by the M1 memset.
// ---------------------------------------------------------------------------
__global__ __launch_bounds__(256) void prep_hist(
    const float* __restrict__ W, const float* __restrict__ bias,
    const float* __restrict__ gamma, const float* __restrict__ beta,
    const float* __restrict__ rmean, const float* __restrict__ rvar,
    const int* __restrict__ ei, short* __restrict__ Wsw,
    float* __restrict__ scsh, int* __restrict__ bhist) {
  __shared__ int lh[NBUK];
  const int t = threadIdx.x;
  const int i = blockIdx.x * 256 + t;
  if (i < CC * CC) {
    const int k = i >> 7, n = i & 127;
    const int nt = n & 7, m = n >> 3;
    const int kb = k >> 5, q = (k >> 3) & 3, j = k & 7;
    Wsw[(size_t)(((nt * 4 + kb) * 64 + (m + 16 * q)) * 8 + j)] = f2bf(W[i]);
  }
  if (i < CC) {
    const float sc = gamma[i] * rsqrtf(rvar[i] + BN_EPS);
    scsh[i] = sc;
    scsh[CC + i] = beta[i] - rmean[i] * sc;
    scsh[2 * CC + i] = bias[i];
  }
  lh[t] = 0;
  __syncthreads();
  const int e0 = blockIdx.x * ACH;
  const int e1 = min(NE, e0 + ACH);
  for (int e = e0 + t; e < e1; e += 256) atomicAdd(&lh[ei[NE + e] / DPB], 1);
  __syncthreads();
  if (lh[t]) atomicAdd(&bhist[t], lh[t]);
}

// ---------------------------------------------------------------------------
// K2: blocks [0,scat): bucket_scatter — chunk-sort 4096 edges by bucket in
// LDS, reserve contiguous global runs, write ebuf coalesced. blocks
// [scat,..): linear_mfma — h = bf16(x@W+b), LDS-staged input, MFMA, direct
// row-major bf16x8 stores (r8-era proven).
// ---------------------------------------------------------------------------
__global__ __launch_bounds__(256) void scatter_linear(
    const int* __restrict__ ei, const int* __restrict__ bhist,
    int* __restrict__ gcurz, int2* __restrict__ ebuf,
    const float* __restrict__ x, const short* __restrict__ Wsw,
    const float* __restrict__ scsh, short* __restrict__ hout,
    int scat) {
  __shared__ int2 sorted[ACH];  // 32 KB (linear role aliases as bf16 tile)
  __shared__ int gsc[NBUK], lh[NBUK], lex[NBUK], rb[NBUK], lc[NBUK];
  const int t = threadIdx.x;

  if (blockIdx.x < scat) {
    // ----- scatter role -----
    const int e0 = blockIdx.x * ACH;
    const int e1 = min(NE, e0 + ACH);
    const int gbase = excl_scan256(gsc, t, bhist[t]);
    lh[t] = 0;
    __syncthreads();
    for (int e = e0 + t; e < e1; e += 256) atomicAdd(&lh[ei[NE + e] / DPB], 1);
    __syncthreads();
    const int vh = lh[t];
    const int lbase = excl_scan256(lex, t, vh);
    lc[t] = lbase;
    if (vh > 0) rb[t] = gbase + atomicAdd(&gcurz[t], vh);
    __syncthreads();
    for (int e = e0 + t; e < e1; e += 256) {
      const int src = ei[e], dst = ei[NE + e];
      const int p = atomicAdd(&lc[dst / DPB], 1);
      sorted[p] = make_int2(src, dst);
    }
    __syncthreads();
    const int n = e1 - e0;
    for (int i = t; i < n; i += 256) {
      const int2 v = sorted[i];
      const int b = v.y / DPB;
      ebuf[rb[b] + (i - lex[b])] = v;
    }
    return;
  }

  // ----- linear role -----
  short* lsA = (short*)sorted;  // 64*LSTR*2 = 17.4 KB <= 32 KB
  const int n0 = (blockIdx.x - scat) * 64;

#pragma unroll
  for (int j = 0; j < 8; ++j) {
    const int idx = j * 256 + t;
    const int row = idx >> 5, kc4 = idx & 31;
    float4 v = make_float4(0.f, 0.f, 0.f, 0.f);
    if (n0 + row < NN) v = *(const float4*)(x + (size_t)(n0 + row) * CC + kc4 * 4);
    short4 sv;
    sv.x = f2bf(v.x); sv.y = f2bf(v.y); sv.z = f2bf(v.z); sv.w = f2bf(v.w);
    *(short4*)(lsA + row * LSTR + kc4 * 4) = sv;
  }
  __syncthreads();

  const int wave = t >> 6, lane = t & 63;
  const int quad = lane >> 4, m = lane & 15;
  const int rowbase = n0 + wave * 16;

  f32x4 acc[8];
#pragma unroll
  for (int nt = 0; nt < 8; ++nt) acc[nt] = (f32x4){0.f, 0.f, 0.f, 0.f};

#pragma unroll
  for (int kb = 0; kb < 4; ++kb) {
    const bf16x8 a =
        *(const bf16x8*)(lsA + (wave * 16 + m) * LSTR + kb * 32 + quad * 8);
#pragma unroll
    for (int nt = 0; nt < 8; ++nt) {
      bf16x8 bb = *(const bf16x8*)(Wsw + (size_t)(((nt * 4 + kb) * 64 + lane) * 8));
      acc[nt] = __builtin_amdgcn_mfma_f32_16x16x32_bf16(a, bb, acc[nt], 0, 0, 0);
    }
  }

  const float4 b0 = *(const float4*)(scsh + 2 * CC + m * 8);
  const float4 b1 = *(const float4*)(scsh + 2 * CC + m * 8 + 4);
  const float bv[8] = {b0.x, b0.y, b0.z, b0.w, b1.x, b1.y, b1.z, b1.w};

#pragma unroll
  for (int reg = 0; reg < 4; ++reg) {
    const int R = rowbase + quad * 4 + reg;
    if (R >= NN) continue;
    bf16x8 hv;
#pragma unroll
    for (int nt = 0; nt < 8; ++nt) hv[nt] = f2bf(acc[nt][reg] + bv[nt]);
    *(bf16x8*)(hout + (size_t)R * CC + m * 8) = hv;
  }
}

// ---------------------------------------------------------------------------
// K3: one 1024-thread block per bucket. segbase from LDS scan of bhist;
// per-dst histogram + scan -> off[]; scatter srcs into LDS csr segment;
// coalesced copy-out.
// ---------------------------------------------------------------------------
__global__ __launch_bounds__(1024) void bucket_to_csr(
    const int2* __restrict__ ebuf, const int* __restrict__ bhist,
    int* __restrict__ off, int* __restrict__ csr) {
  __shared__ int gs[NBUK];
  __shared__ int dh[512];
  __shared__ int s[512];
  __shared__ int lcur[512];
  __shared__ int lcsr[CAP];  // 40 KB
  const int b = blockIdx.x, t = threadIdx.x;

  if (t < NBUK) gs[t] = bhist[t];
  __syncthreads();
  for (int d = 1; d < NBUK; d <<= 1) {
    int a0 = 0;
    if (t < NBUK && t >= d) a0 = gs[t - d];
    __syncthreads();
    if (t < NBUK) gs[t] += a0;
    __syncthreads();
  }
  const int seglen = bhist[b];
  const int segbase = gs[b] - seglen;
  const int lo = b * DPB;
  const int hi = min(NN, lo + DPB);
  const int nd = hi - lo;
  const int2* eb = ebuf + segbase;

  if (t < 512) dh[t] = 0;
  __syncthreads();
  for (int i = t; i < seglen; i += 1024) atomicAdd(&dh[eb[i].y - lo], 1);
  __syncthreads();

  if (t < 512) s[t] = dh[t];
  __syncthreads();
  for (int d = 1; d < 512; d <<= 1) {
    int a0 = 0;
    if (t < 512 && t >= d) a0 = s[t - d];
    __syncthreads();
    if (t < 512) s[t] += a0;
    __syncthreads();
  }
  if (t < 512) lcur[t] = s[t] - dh[t];  // exclusive
  if (t < nd) off[lo + t] = segbase + (s[t] - dh[t]);
  if (b == NBUK - 1 && t == 0) off[NN] = NE;
  __syncthreads();

  if (seglen <= CAP) {
    for (int i = t; i < seglen; i += 1024) {
      const int2 e = eb[i];
      const int p = atomicAdd(&lcur[e.y - lo], 1);
      lcsr[p] = e.x;
    }
    __syncthreads();
    for (int i = t; i < seglen; i += 1024) csr[segbase + i] = lcsr[i];
  } else {
    for (int i = t; i < seglen; i += 1024) {
      const int2 e = eb[i];
      const int p = atomicAdd(&lcur[e.y - lo], 1);
      csr[segbase + p] = e.x;
    }
  }
}

// ---------------------------------------------------------------------------
// K4: full-row e4xc16 gather. Block = 64 nodes; loff + csr segment staged in
// LDS (6.4KB). Wave = one node at a time (uniform trip count, 16 nodes
// serial per wave); lane = (e4 = lane>>4, c16 = lane&15). Per iteration one
// dwordx4 VMEM instr = 4 edges x full 256B rows; csr via ds_read (4 words,
// 16-way broadcast); 2-deep unroll. Epilogue: shfl_xor(16,32) reduce + BN
// on e4==0 lanes (512B contiguous store); BN consts hoisted per wave.
// ---------------------------------------------------------------------------
__global__ __launch_bounds__(256) void gather_bn_relu(
    const short* __restrict__ h, const int* __restrict__ off,
    const int* __restrict__ csr, const float* __restrict__ scsh,
    float* __restrict__ out) {
  __shared__ int loff[GNB + 1];
  __shared__ int lcsr[CAP2];  // 6 KB
  const int nb0 = blockIdx.x * GNB;
  const int t = threadIdx.x;
  const int nnb = min(GNB, NN - nb0);

  for (int i = t; i <= nnb; i += 256) loff[i] = off[nb0 + i];
  __syncthreads();
  const int s0 = loff[0];
  const int seglen = loff[nnb] - s0;
  const int stg = min(seglen, CAP2);
  for (int i = t; i < stg; i += 256) lcsr[i] = csr[s0 + i];
  __syncthreads();

  const int wave = t >> 6, lane = t & 63;
  const int e4 = lane >> 4;    // edge slot 0..3
  const int c16 = lane & 15;   // col block: natural cols c16*8..+7
  const float4 sc0 = *(const float4*)(scsh + c16 * 8);
  const float4 sc1 = *(const float4*)(scsh + c16 * 8 + 4);
  const float4 sh0 = *(const float4*)(scsh + CC + c16 * 8);
  const float4 sh1 = *(const float4*)(scsh + CC + c16 * 8 + 4);

  const int lEnd = min(nnb, wave * 16 + 16);
  const bool inl = (seglen <= CAP2);
  for (int l = wave * 16; l < lEnd; ++l) {
    const int s = inl ? loff[l] - s0 : loff[l];
    const int e = inl ? loff[l + 1] - s0 : loff[l + 1];
    float a0 = 0.f, a1 = 0.f, a2 = 0.f, a3 = 0.f;
    float a4 = 0.f, a5 = 0.f, a6 = 0.f, a7 = 0.f;
    int i = s + e4;
    for (; i + 4 < e; i += 8) {
      const int q0 = inl ? lcsr[i] : csr[i];
      const int q1 = inl ? lcsr[i + 4] : csr[i + 4];
      const uint4 p0 = *(const uint4*)(h + (size_t)q0 * CC + c16 * 8);
      const uint4 p1 = *(const uint4*)(h + (size_t)q1 * CC + c16 * 8);
      a0 += bflo(p0.x) + bflo(p1.x); a1 += bfhi(p0.x) + bfhi(p1.x);
      a2 += bflo(p0.y) + bflo(p1.y); a3 += bfhi(p0.y) + bfhi(p1.y);
      a4 += bflo(p0.z) + bflo(p1.z); a5 += bfhi(p0.z) + bfhi(p1.z);
      a6 += bflo(p0.w) + bflo(p1.w); a7 += bfhi(p0.w) + bfhi(p1.w);
    }
    if (i < e) {
      const int q = inl ? lcsr[i] : csr[i];
      const uint4 p = *(const uint4*)(h + (size_t)q * CC + c16 * 8);
      a0 += bflo(p.x); a1 += bfhi(p.x);
      a2 += bflo(p.y); a3 += bfhi(p.y);
      a4 += bflo(p.z); a5 += bfhi(p.z);
      a6 += bflo(p.w); a7 += bfhi(p.w);
    }
    // reduce across the 4 e4 groups (lane bits 4,5)
    a0 += __shfl_xor(a0, 16); a1 += __shfl_xor(a1, 16);
    a2 += __shfl_xor(a2, 16); a3 += __shfl_xor(a3, 16);
    a4 += __shfl_xor(a4, 16); a5 += __shfl_xor(a5, 16);
    a6 += __shfl_xor(a6, 16); a7 += __shfl_xor(a7, 16);
    a0 += __shfl_xor(a0, 32); a1 += __shfl_xor(a1, 32);
    a2 += __shfl_xor(a2, 32); a3 += __shfl_xor(a3, 32);
    a4 += __shfl_xor(a4, 32); a5 += __shfl_xor(a5, 32);
    a6 += __shfl_xor(a6, 32); a7 += __shfl_xor(a7, 32);
    if (e4 == 0) {
      const float inv = (e > s) ? 1.0f / (float)(e - s) : 0.0f;
      float4 o0, o1;
      o0.x = fmaxf(0.f, a0 * inv * sc0.x + sh0.x);
      o0.y = fmaxf(0.f, a1 * inv * sc0.y + sh0.y);
      o0.z = fmaxf(0.f, a2 * inv * sc0.z + sh0.z);
      o0.w = fmaxf(0.f, a3 * inv * sc0.w + sh0.w);
      o1.x = fmaxf(0.f, a4 * inv * sc1.x + sh1.x);
      o1.y = fmaxf(0.f, a5 * inv * sc1.y + sh1.y);
      o1.z = fmaxf(0.f, a6 * inv * sc1.z + sh1.z);
      o1.w = fmaxf(0.f, a7 * inv * sc1.w + sh1.w);
      float* op = out + (size_t)(nb0 + l) * CC + c16 * 8;
      *(float4*)op = o0;
      *(float4*)(op + 4) = o1;
    }
  }
}

// ---------------------------------------------------------------------------
// Fallback (small ws): atomic scatter + fp32 vector GEMM.
// ---------------------------------------------------------------------------
__global__ __launch_bounds__(256) void edge_scatter(
    const float* __restrict__ x, const int* __restrict__ ei,
    float* __restrict__ sums, int* __restrict__ cnt) {
  int gt = blockIdx.x * 256 + threadIdx.x;
  int e = gt >> 5;
  int sub = gt & 31;
  if (e >= NE) return;
  int src = ei[e];
  int dst = ei[NE + e];
  const float4 v = *(const float4*)(x + (size_t)src * CC + sub * 4);
  float* o = sums + (size_t)dst * CC + sub * 4;
  unsafeAtomicAdd(o + 0, v.x);
  unsafeAtomicAdd(o + 1, v.y);
  unsafeAtomicAdd(o + 2, v.z);
  unsafeAtomicAdd(o + 3, v.w);
  if (sub == 0) atomicAdd(cnt + dst, 1);
}

__global__ __launch_bounds__(256) void gemm_bn_relu_fb(
    float* buf, const float* __restrict__ W, const float* __restrict__ bias,
    const float* __restrict__ gamma, const float* __restrict__ beta,
    const float* __restrict__ rmean, const float* __restrict__ rvar,
    const int* __restrict__ cnt) {
  __shared__ float xsT[CC][65];
  const int t = threadIdx.x;
  const int n0 = blockIdx.x * 64;
  for (int j = 0; j < 8; ++j) {
    int i = t + 256 * j;
    int row = i >> 5;
    int ko = (i & 31) * 4;
    float4 v = make_float4(0.f, 0.f, 0.f, 0.f);
    if (n0 + row < NN) v = *(const float4*)(buf + (size_t)(n0 + row) * CC + ko);
    xsT[ko + 0][row] = v.x;
    xsT[ko + 1][row] = v.y;
    xsT[ko + 2][row] = v.z;
    xsT[ko + 3][row] = v.w;
  }
  __syncthreads();
  const int cg = t & 31;
  const int ng8 = (t >> 5) * 8;
  float acc[8][4];
#pragma unroll
  for (int j = 0; j < 8; ++j)
#pragma unroll
    for (int c = 0; c < 4; ++c) acc[j][c] = 0.f;
#pragma unroll 8
  for (int k = 0; k < CC; ++k) {
    const float4 wv = *(const float4*)(W + k * CC + cg * 4);
#pragma unroll
    for (int j = 0; j < 8; ++j) {
      const float xv = xsT[k][ng8 + j];
      acc[j][0] = fmaf(xv, wv.x, acc[j][0]);
      acc[j][1] = fmaf(xv, wv.y, acc[j][1]);
      acc[j][2] = fmaf(xv, wv.z, acc[j][2]);
      acc[j][3] = fmaf(xv, wv.w, acc[j][3]);
    }
  }
  const float4 bb = *(const float4*)(bias + cg * 4);
  const float4 gg = *(const float4*)(gamma + cg * 4);
  const float4 bt = *(const float4*)(beta + cg * 4);
  const float4 mu = *(const float4*)(rmean + cg * 4);
  const float4 vr = *(const float4*)(rvar + cg * 4);
  float sc[4], sh[4];
  sc[0] = gg.x * rsqrtf(vr.x + BN_EPS);
  sc[1] = gg.y * rsqrtf(vr.y + BN_EPS);
  sc[2] = gg.z * rsqrtf(vr.z + BN_EPS);
  sc[3] = gg.w * rsqrtf(vr.w + BN_EPS);
  sh[0] = bt.x - mu.x * sc[0];
  sh[1] = bt.y - mu.y * sc[1];
  sh[2] = bt.z - mu.z * sc[2];
  sh[3] = bt.w - mu.w * sc[3];
#pragma unroll
  for (int j = 0; j < 8; ++j) {
    const int n = n0 + ng8 + j;
    if (n >= NN) continue;
    const int cn = cnt[n];
    const float inv = cn > 0 ? 1.0f / (float)cn : 0.0f;
    const float bsel = cn > 0 ? 1.0f : 0.0f;
    float4 o;
    o.x = fmaxf(0.f, (acc[j][0] * inv + bsel * bb.x) * sc[0] + sh[0]);
    o.y = fmaxf(0.f, (acc[j][1] * inv + bsel * bb.y) * sc[1] + sh[1]);
    o.z = fmaxf(0.f, (acc[j][2] * inv + bsel * bb.z) * sc[2] + sh[2]);
    o.w = fmaxf(0.f, (acc[j][3] * inv + bsel * bb.w) * sc[3] + sh[3]);
    *(float4*)(buf + (size_t)n * CC + cg * 4) = o;
  }
}

extern "C" void kernel_launch(void* const* d_in, const int* in_sizes, int n_in,
                              void* d_out, int out_size, void* d_ws, size_t ws_size,
                              hipStream_t stream) {
  const float* x     = (const float*)d_in[0];
  const int*   ei    = (const int*)d_in[1];
  const float* W     = (const float*)d_in[2];
  const float* bias  = (const float*)d_in[3];
  const float* gamma = (const float*)d_in[4];
  const float* beta  = (const float*)d_in[5];
  const float* rmean = (const float*)d_in[6];
  const float* rvar  = (const float*)d_in[7];
  float* out = (float*)d_out;

  // ws layout (bytes):
  //   off[NN+1] | bhist[256] | gcurz[256] (contiguous -> one 2KB memset)
  //   | csr[NE] | scsh[384f] | Wsw[16384 bf16] | ebuf int2[NE] | h[NN*CC bf16]
  const size_t OFF_B  = 0;
  const size_t BH_B   = 400128;
  const size_t GC_B   = 401152;
  const size_t CSR_B  = 802304;
  const size_t SCSH_B = 7202304;
  const size_t WSW_B  = 7204352;
  const size_t EB_B   = 7237120;
  const size_t H1_B   = 20037120;                     // tier-1 h (after ebuf)
  const size_t NEED1  = H1_B + (size_t)NN * CC * 2;   // 45,637,120
  const size_t NEED2  = EB_B + (size_t)NN * CC * 2;   // 32,837,120 (alias)

  const int GGRID = (NN + GNB - 1) / GNB;  // 1563 blocks (no slicing)

  if (ws_size >= NEED2) {
    int*   off   = (int*)((char*)d_ws + OFF_B);
    int*   bhist = (int*)((char*)d_ws + BH_B);
    int*   gcurz = (int*)((char*)d_ws + GC_B);
    int*   csr   = (int*)((char*)d_ws + CSR_B);
    float* scsh  = (float*)((char*)d_ws + SCSH_B);
    short* Wsw   = (short*)((char*)d_ws + WSW_B);

    hipMemsetAsync(bhist, 0, 2048, stream);  // bhist + gcurz
    prep_hist<<<ABLK, 256, 0, stream>>>(W, bias, gamma, beta, rmean, rvar,
                                        ei, Wsw, scsh, bhist);
    if (ws_size >= NEED1) {
      // tier 1: fused scatter+linear (ebuf and h distinct)
      int2*  ebuf = (int2*)((char*)d_ws + EB_B);
      short* h    = (short*)((char*)d_ws + H1_B);
      scatter_linear<<<ABLK + LBLK, 256, 0, stream>>>(
          ei, bhist, gcurz, ebuf, x, Wsw, scsh, h, ABLK);
      bucket_to_csr<<<NBUK, 1024, 0, stream>>>(ebuf, bhist, off, csr);
      gather_bn_relu<<<GGRID, 256, 0, stream>>>(h, off, csr, scsh, out);
    } else {
      // tier 2: un-fused, ebuf aliases h (r8-proven ordering)
      int2*  ebuf = (int2*)((char*)d_ws + EB_B);
      short* h    = (short*)((char*)d_ws + EB_B);
      scatter_linear<<<ABLK, 256, 0, stream>>>(
          ei, bhist, gcurz, ebuf, x, Wsw, scsh, h, ABLK);  // scatter only
      bucket_to_csr<<<NBUK, 1024, 0, stream>>>(ebuf, bhist, off, csr);
      scatter_linear<<<LBLK, 256, 0, stream>>>(
          ei, bhist, gcurz, ebuf, x, Wsw, scsh, h, 0);     // linear only
      gather_bn_relu<<<GGRID, 256, 0, stream>>>(h, off, csr, scsh, out);
    }
  } else {
    int* cnt = (int*)d_ws;
    hipMemsetAsync(out, 0, (size_t)NN * CC * sizeof(float), stream);
    hipMemsetAsync(cnt, 0, (size_t)NN * sizeof(int), stream);
    edge_scatter<<<(NE * 32) / 256, 256, 0, stream>>>(x, ei, out, cnt);
    gemm_bn_relu_fb<<<(NN + 63) / 64, 256, 0, stream>>>(
        out, W, bias, gamma, beta, rmean, rvar, cnt);
  }
}

// Round 8
// 221.508 us; speedup vs baseline: 5.3670x; 1.0035x over previous
//
#include <hip/hip_runtime.h>

// GCN layer on MI355X — round 17: Wsw-in-LDS linear + packed ebuf.
// Gather is settled at 64.1us (r16 e4xc16 full-row dwordx4; TA-request
// floor for bf16). Remaining mass is the ~158us non-gather "rest": K2's
// linear role re-read Wsw (32KB) from global per block = 200k VMEM instrs
// = 12.8M lane-requests ~ 200MB L2 traffic across 1563 blocks. Now staged
// once per block into LDS (ds_read_b128 B-operands, conflict-free).
// ebuf packed to one int (src<<9|dst_local): -12.8MB traffic, tier-1 ws
// NEED down to 39.2MB.
//   M1:  memsetAsync(bhist+gcurz, 0, 2KB)
//   K1 prep_hist:      Wsw swizzle + BN consts FUSED with bucket histogram
//   K2 scatter_linear: bucket_scatter (391, packed ebuf) FUSED with
//                      linear_mfma (1563, Wsw in LDS); manual smem union
//                      49KB -> 3 blocks/CU.
//   K3 bucket_to_csr:  1024 threads/block, packed ebuf input.
//   K4 gather_bn_relu: r16 verbatim (64.1us proven).
// mean(h[src]) = mean(x[src])@W + b (linearity); deg=0 -> sum=0 -> relu(sh).

#define NN 100000
#define NE 1600000
#define CC 128
#define BN_EPS 1e-5f
#define LBLK 1563     // ceil(NN/64) linear blocks
#define LSTR 136      // LDS row stride in bf16 (128 + 8 pad)
#define NBUK 256      // dst buckets
#define DPB 391       // dsts per bucket (256*391 = 100096 >= NN)
#define ACH 4096      // edges per scatter block
#define ABLK 391      // ceil(NE/ACH)
#define CAP 10240     // to_csr LDS segment capacity (mean 6250, huge margin)
#define GNB 64        // nodes per gather block
#define CAP2 1536     // gather csr LDS cap (mean 1024, sd 32: +16sigma)

typedef __attribute__((ext_vector_type(8))) short bf16x8;
typedef __attribute__((ext_vector_type(4))) float f32x4;

static __device__ __forceinline__ short f2bf(float f) {
  union { float f; unsigned u; } v; v.f = f;
  unsigned r = (v.u + 0x7FFF + ((v.u >> 16) & 1)) >> 16;  // RNE
  return (short)r;
}
static __device__ __forceinline__ float bflo(unsigned p) {
  return __uint_as_float(p << 16);
}
static __device__ __forceinline__ float bfhi(unsigned p) {
  return __uint_as_float(p & 0xffff0000u);
}

// 256-wide Hillis-Steele scan in LDS; leaves a[] exclusive, returns excl[t].
// (256-thread blocks only.)
static __device__ __forceinline__ int excl_scan256(int* a, int t, int v) {
  a[t] = v;
  __syncthreads();
  for (int d = 1; d < 256; d <<= 1) {
    const int x = (t >= d) ? a[t - d] : 0;
    __syncthreads();
    a[t] += x;
    __syncthreads();
  }
  const int incl = a[t];
  __syncthreads();
  a[t] = incl - v;
  __syncthreads();
  return incl - v;
}

// ---------------------------------------------------------------------------
// K1: prep (Wsw swizzle, col-permuted so D-lane m holds natural cols m*8..+7;
// BN scale/shift + bias) on blocks 0-63, bucket histogram on all 391 blocks.
// bhist pre-zeroed by the M1 memset.
// ---------------------------------------------------------------------------
__global__ __launch_bounds__(256) void prep_hist(
    const float* __restrict__ W, const float* __restrict__ bias,
    const float* __restrict__ gamma, const float* __restrict__ beta,
    const float* __restrict__ rmean, const float* __restrict__ rvar,
    const int* __restrict__ ei, short* __restrict__ Wsw,
    float* __restrict__ scsh, int* __restrict__ bhist) {
  __shared__ int lh[NBUK];
  const int t = threadIdx.x;
  const int i = blockIdx.x * 256 + t;
  if (i < CC * CC) {
    const int k = i >> 7, n = i & 127;
    const int nt = n & 7, m = n >> 3;
    const int kb = k >> 5, q = (k >> 3) & 3, j = k & 7;
    Wsw[(size_t)(((nt * 4 + kb) * 64 + (m + 16 * q)) * 8 + j)] = f2bf(W[i]);
  }
  if (i < CC) {
    const float sc = gamma[i] * rsqrtf(rvar[i] + BN_EPS);
    scsh[i] = sc;
    scsh[CC + i] = beta[i] - rmean[i] * sc;
    scsh[2 * CC + i] = bias[i];
  }
  lh[t] = 0;
  __syncthreads();
  const int e0 = blockIdx.x * ACH;
  const int e1 = min(NE, e0 + ACH);
  for (int e = e0 + t; e < e1; e += 256) atomicAdd(&lh[ei[NE + e] / DPB], 1);
  __syncthreads();
  if (lh[t]) atomicAdd(&bhist[t], lh[t]);
}

// ---------------------------------------------------------------------------
// K2: blocks [0,scat): bucket_scatter — chunk-sort 4096 edges by bucket in
// LDS, reserve contiguous global runs, write PACKED ebuf ((src<<9)|dstlocal)
// coalesced. blocks [scat,..): linear_mfma — h = bf16(x@W+b): x staged to
// LDS bf16, Wsw staged to LDS ONCE (kills the per-block 32KB global re-read
// = 12.8M lane-requests pipeline-wide), MFMA, direct row-major stores.
// Manual smem union: scatter 37.9KB | linear 49.4KB.
// ---------------------------------------------------------------------------
__global__ __launch_bounds__(256) void scatter_linear(
    const int* __restrict__ ei, const int* __restrict__ bhist,
    int* __restrict__ gcurz, int* __restrict__ ebuf,
    const float* __restrict__ x, const short* __restrict__ Wsw,
    const float* __restrict__ scsh, short* __restrict__ hout,
    int scat) {
  __shared__ __align__(16) char smem[50176];
  const int t = threadIdx.x;

  if (blockIdx.x < scat) {
    // ----- scatter role -----
    int2* sorted = (int2*)smem;                 // 32768
    int*  gsc    = (int*)(smem + 32768);        // +1024
    int*  lh     = (int*)(smem + 33792);
    int*  lex    = (int*)(smem + 34816);
    int*  rb     = (int*)(smem + 35840);
    int*  lc     = (int*)(smem + 36864);        // end 37888
    const int e0 = blockIdx.x * ACH;
    const int e1 = min(NE, e0 + ACH);
    const int gbase = excl_scan256(gsc, t, bhist[t]);
    lh[t] = 0;
    __syncthreads();
    for (int e = e0 + t; e < e1; e += 256) atomicAdd(&lh[ei[NE + e] / DPB], 1);
    __syncthreads();
    const int vh = lh[t];
    const int lbase = excl_scan256(lex, t, vh);
    lc[t] = lbase;
    if (vh > 0) rb[t] = gbase + atomicAdd(&gcurz[t], vh);
    __syncthreads();
    for (int e = e0 + t; e < e1; e += 256) {
      const int src = ei[e], dst = ei[NE + e];
      const int p = atomicAdd(&lc[dst / DPB], 1);
      sorted[p] = make_int2(src, dst);
    }
    __syncthreads();
    const int n = e1 - e0;
    for (int i = t; i < n; i += 256) {
      const int2 v = sorted[i];
      const int b = v.y / DPB;
      ebuf[rb[b] + (i - lex[b])] = (v.x << 9) | (v.y - b * DPB);
    }
    return;
  }

  // ----- linear role -----
  short* lsA = (short*)smem;            // 64*LSTR*2 = 17408
  short* lsW = (short*)(smem + 17408);  // 32768 -> end 50176
  const int n0 = (blockIdx.x - scat) * 64;

#pragma unroll
  for (int j = 0; j < 8; ++j) {
    const int idx = j * 256 + t;
    const int row = idx >> 5, kc4 = idx & 31;
    float4 v = make_float4(0.f, 0.f, 0.f, 0.f);
    if (n0 + row < NN) v = *(const float4*)(x + (size_t)(n0 + row) * CC + kc4 * 4);
    short4 sv;
    sv.x = f2bf(v.x); sv.y = f2bf(v.y); sv.z = f2bf(v.z); sv.w = f2bf(v.w);
    *(short4*)(lsA + row * LSTR + kc4 * 4) = sv;
  }
  // stage Wsw (32KB) once per block: 8 x bf16x8 per thread, coalesced
#pragma unroll
  for (int j = 0; j < 8; ++j) {
    const int idx = j * 256 + t;
    *(bf16x8*)(lsW + (size_t)idx * 8) = *(const bf16x8*)(Wsw + (size_t)idx * 8);
  }
  __syncthreads();

  const int wave = t >> 6, lane = t & 63;
  const int quad = lane >> 4, m = lane & 15;
  const int rowbase = n0 + wave * 16;

  f32x4 acc[8];
#pragma unroll
  for (int nt = 0; nt < 8; ++nt) acc[nt] = (f32x4){0.f, 0.f, 0.f, 0.f};

#pragma unroll
  for (int kb = 0; kb < 4; ++kb) {
    const bf16x8 a =
        *(const bf16x8*)(lsA + (wave * 16 + m) * LSTR + kb * 32 + quad * 8);
#pragma unroll
    for (int nt = 0; nt < 8; ++nt) {
      const bf16x8 bb = *(const bf16x8*)(lsW + (size_t)(((nt * 4 + kb) * 64 + lane) * 8));
      acc[nt] = __builtin_amdgcn_mfma_f32_16x16x32_bf16(a, bb, acc[nt], 0, 0, 0);
    }
  }

  const float4 b0 = *(const float4*)(scsh + 2 * CC + m * 8);
  const float4 b1 = *(const float4*)(scsh + 2 * CC + m * 8 + 4);
  const float bv[8] = {b0.x, b0.y, b0.z, b0.w, b1.x, b1.y, b1.z, b1.w};

#pragma unroll
  for (int reg = 0; reg < 4; ++reg) {
    const int R = rowbase + quad * 4 + reg;
    if (R >= NN) continue;
    bf16x8 hv;
#pragma unroll
    for (int nt = 0; nt < 8; ++nt) hv[nt] = f2bf(acc[nt][reg] + bv[nt]);
    *(bf16x8*)(hout + (size_t)R * CC + m * 8) = hv;
  }
}

// ---------------------------------------------------------------------------
// K3: one 1024-thread block per bucket, packed ebuf. segbase from LDS scan
// of bhist; per-dst histogram + scan -> off[]; scatter srcs into LDS csr
// segment; coalesced copy-out.
// ---------------------------------------------------------------------------
__global__ __launch_bounds__(1024) void bucket_to_csr(
    const int* __restrict__ ebuf, const int* __restrict__ bhist,
    int* __restrict__ off, int* __restrict__ csr) {
  __shared__ int gs[NBUK];
  __shared__ int dh[512];
  __shared__ int s[512];
  __shared__ int lcur[512];
  __shared__ int lcsr[CAP];  // 40 KB
  const int b = blockIdx.x, t = threadIdx.x;

  if (t < NBUK) gs[t] = bhist[t];
  __syncthreads();
  for (int d = 1; d < NBUK; d <<= 1) {
    int a0 = 0;
    if (t < NBUK && t >= d) a0 = gs[t - d];
    __syncthreads();
    if (t < NBUK) gs[t] += a0;
    __syncthreads();
  }
  const int seglen = bhist[b];
  const int segbase = gs[b] - seglen;
  const int lo = b * DPB;
  const int hi = min(NN, lo + DPB);
  const int nd = hi - lo;
  const int* eb = ebuf + segbase;

  if (t < 512) dh[t] = 0;
  __syncthreads();
  for (int i = t; i < seglen; i += 1024) atomicAdd(&dh[eb[i] & 511], 1);
  __syncthreads();

  if (t < 512) s[t] = dh[t];
  __syncthreads();
  for (int d = 1; d < 512; d <<= 1) {
    int a0 = 0;
    if (t < 512 && t >= d) a0 = s[t - d];
    __syncthreads();
    if (t < 512) s[t] += a0;
    __syncthreads();
  }
  if (t < 512) lcur[t] = s[t] - dh[t];  // exclusive
  if (t < nd) off[lo + t] = segbase + (s[t] - dh[t]);
  if (b == NBUK - 1 && t == 0) off[NN] = NE;
  __syncthreads();

  if (seglen <= CAP) {
    for (int i = t; i < seglen; i += 1024) {
      const int e = eb[i];
      const int p = atomicAdd(&lcur[e & 511], 1);
      lcsr[p] = (int)((unsigned)e >> 9);
    }
    __syncthreads();
    for (int i = t; i < seglen; i += 1024) csr[segbase + i] = lcsr[i];
  } else {
    for (int i = t; i < seglen; i += 1024) {
      const int e = eb[i];
      const int p = atomicAdd(&lcur[e & 511], 1);
      csr[segbase + p] = (int)((unsigned)e >> 9);
    }
  }
}

// ---------------------------------------------------------------------------
// K4: full-row e4xc16 gather (r16 verbatim, 64.1us proven). Block = 64
// nodes; loff + csr segment staged in LDS. Wave = one node at a time; lane =
// (e4 = lane>>4, c16 = lane&15). One dwordx4 = 4 edges x 256B rows; csr via
// ds_read; epilogue shfl_xor(16,32) + BN on e4==0 lanes.
// ---------------------------------------------------------------------------
__global__ __launch_bounds__(256) void gather_bn_relu(
    const short* __restrict__ h, const int* __restrict__ off,
    const int* __restrict__ csr, const float* __restrict__ scsh,
    float* __restrict__ out) {
  __shared__ int loff[GNB + 1];
  __shared__ int lcsr[CAP2];  // 6 KB
  const int nb0 = blockIdx.x * GNB;
  const int t = threadIdx.x;
  const int nnb = min(GNB, NN - nb0);

  for (int i = t; i <= nnb; i += 256) loff[i] = off[nb0 + i];
  __syncthreads();
  const int s0 = loff[0];
  const int seglen = loff[nnb] - s0;
  const int stg = min(seglen, CAP2);
  for (int i = t; i < stg; i += 256) lcsr[i] = csr[s0 + i];
  __syncthreads();

  const int wave = t >> 6, lane = t & 63;
  const int e4 = lane >> 4;    // edge slot 0..3
  const int c16 = lane & 15;   // col block: natural cols c16*8..+7
  const float4 sc0 = *(const float4*)(scsh + c16 * 8);
  const float4 sc1 = *(const float4*)(scsh + c16 * 8 + 4);
  const float4 sh0 = *(const float4*)(scsh + CC + c16 * 8);
  const float4 sh1 = *(const float4*)(scsh + CC + c16 * 8 + 4);

  const int lEnd = min(nnb, wave * 16 + 16);
  const bool inl = (seglen <= CAP2);
  for (int l = wave * 16; l < lEnd; ++l) {
    const int s = inl ? loff[l] - s0 : loff[l];
    const int e = inl ? loff[l + 1] - s0 : loff[l + 1];
    float a0 = 0.f, a1 = 0.f, a2 = 0.f, a3 = 0.f;
    float a4 = 0.f, a5 = 0.f, a6 = 0.f, a7 = 0.f;
    int i = s + e4;
    for (; i + 4 < e; i += 8) {
      const int q0 = inl ? lcsr[i] : csr[i];
      const int q1 = inl ? lcsr[i + 4] : csr[i + 4];
      const uint4 p0 = *(const uint4*)(h + (size_t)q0 * CC + c16 * 8);
      const uint4 p1 = *(const uint4*)(h + (size_t)q1 * CC + c16 * 8);
      a0 += bflo(p0.x) + bflo(p1.x); a1 += bfhi(p0.x) + bfhi(p1.x);
      a2 += bflo(p0.y) + bflo(p1.y); a3 += bfhi(p0.y) + bfhi(p1.y);
      a4 += bflo(p0.z) + bflo(p1.z); a5 += bfhi(p0.z) + bfhi(p1.z);
      a6 += bflo(p0.w) + bflo(p1.w); a7 += bfhi(p0.w) + bfhi(p1.w);
    }
    if (i < e) {
      const int q = inl ? lcsr[i] : csr[i];
      const uint4 p = *(const uint4*)(h + (size_t)q * CC + c16 * 8);
      a0 += bflo(p.x); a1 += bfhi(p.x);
      a2 += bflo(p.y); a3 += bfhi(p.y);
      a4 += bflo(p.z); a5 += bfhi(p.z);
      a6 += bflo(p.w); a7 += bfhi(p.w);
    }
    // reduce across the 4 e4 groups (lane bits 4,5)
    a0 += __shfl_xor(a0, 16); a1 += __shfl_xor(a1, 16);
    a2 += __shfl_xor(a2, 16); a3 += __shfl_xor(a3, 16);
    a4 += __shfl_xor(a4, 16); a5 += __shfl_xor(a5, 16);
    a6 += __shfl_xor(a6, 16); a7 += __shfl_xor(a7, 16);
    a0 += __shfl_xor(a0, 32); a1 += __shfl_xor(a1, 32);
    a2 += __shfl_xor(a2, 32); a3 += __shfl_xor(a3, 32);
    a4 += __shfl_xor(a4, 32); a5 += __shfl_xor(a5, 32);
    a6 += __shfl_xor(a6, 32); a7 += __shfl_xor(a7, 32);
    if (e4 == 0) {
      const float inv = (e > s) ? 1.0f / (float)(e - s) : 0.0f;
      float4 o0, o1;
      o0.x = fmaxf(0.f, a0 * inv * sc0.x + sh0.x);
      o0.y = fmaxf(0.f, a1 * inv * sc0.y + sh0.y);
      o0.z = fmaxf(0.f, a2 * inv * sc0.z + sh0.z);
      o0.w = fmaxf(0.f, a3 * inv * sc0.w + sh0.w);
      o1.x = fmaxf(0.f, a4 * inv * sc1.x + sh1.x);
      o1.y = fmaxf(0.f, a5 * inv * sc1.y + sh1.y);
      o1.z = fmaxf(0.f, a6 * inv * sc1.z + sh1.z);
      o1.w = fmaxf(0.f, a7 * inv * sc1.w + sh1.w);
      float* op = out + (size_t)(nb0 + l) * CC + c16 * 8;
      *(float4*)op = o0;
      *(float4*)(op + 4) = o1;
    }
  }
}

// ---------------------------------------------------------------------------
// Fallback (small ws): atomic scatter + fp32 vector GEMM.
// ---------------------------------------------------------------------------
__global__ __launch_bounds__(256) void edge_scatter(
    const float* __restrict__ x, const int* __restrict__ ei,
    float* __restrict__ sums, int* __restrict__ cnt) {
  int gt = blockIdx.x * 256 + threadIdx.x;
  int e = gt >> 5;
  int sub = gt & 31;
  if (e >= NE) return;
  int src = ei[e];
  int dst = ei[NE + e];
  const float4 v = *(const float4*)(x + (size_t)src * CC + sub * 4);
  float* o = sums + (size_t)dst * CC + sub * 4;
  unsafeAtomicAdd(o + 0, v.x);
  unsafeAtomicAdd(o + 1, v.y);
  unsafeAtomicAdd(o + 2, v.z);
  unsafeAtomicAdd(o + 3, v.w);
  if (sub == 0) atomicAdd(cnt + dst, 1);
}

__global__ __launch_bounds__(256) void gemm_bn_relu_fb(
    float* buf, const float* __restrict__ W, const float* __restrict__ bias,
    const float* __restrict__ gamma, const float* __restrict__ beta,
    const float* __restrict__ rmean, const float* __restrict__ rvar,
    const int* __restrict__ cnt) {
  __shared__ float xsT[CC][65];
  const int t = threadIdx.x;
  const int n0 = blockIdx.x * 64;
  for (int j = 0; j < 8; ++j) {
    int i = t + 256 * j;
    int row = i >> 5;
    int ko = (i & 31) * 4;
    float4 v = make_float4(0.f, 0.f, 0.f, 0.f);
    if (n0 + row < NN) v = *(const float4*)(buf + (size_t)(n0 + row) * CC + ko);
    xsT[ko + 0][row] = v.x;
    xsT[ko + 1][row] = v.y;
    xsT[ko + 2][row] = v.z;
    xsT[ko + 3][row] = v.w;
  }
  __syncthreads();
  const int cg = t & 31;
  const int ng8 = (t >> 5) * 8;
  float acc[8][4];
#pragma unroll
  for (int j = 0; j < 8; ++j)
#pragma unroll
    for (int c = 0; c < 4; ++c) acc[j][c] = 0.f;
#pragma unroll 8
  for (int k = 0; k < CC; ++k) {
    const float4 wv = *(const float4*)(W + k * CC + cg * 4);
#pragma unroll
    for (int j = 0; j < 8; ++j) {
      const float xv = xsT[k][ng8 + j];
      acc[j][0] = fmaf(xv, wv.x, acc[j][0]);
      acc[j][1] = fmaf(xv, wv.y, acc[j][1]);
      acc[j][2] = fmaf(xv, wv.z, acc[j][2]);
      acc[j][3] = fmaf(xv, wv.w, acc[j][3]);
    }
  }
  const float4 bb = *(const float4*)(bias + cg * 4);
  const float4 gg = *(const float4*)(gamma + cg * 4);
  const float4 bt = *(const float4*)(beta + cg * 4);
  const float4 mu = *(const float4*)(rmean + cg * 4);
  const float4 vr = *(const float4*)(rvar + cg * 4);
  float sc[4], sh[4];
  sc[0] = gg.x * rsqrtf(vr.x + BN_EPS);
  sc[1] = gg.y * rsqrtf(vr.y + BN_EPS);
  sc[2] = gg.z * rsqrtf(vr.z + BN_EPS);
  sc[3] = gg.w * rsqrtf(vr.w + BN_EPS);
  sh[0] = bt.x - mu.x * sc[0];
  sh[1] = bt.y - mu.y * sc[1];
  sh[2] = bt.z - mu.z * sc[2];
  sh[3] = bt.w - mu.w * sc[3];
#pragma unroll
  for (int j = 0; j < 8; ++j) {
    const int n = n0 + ng8 + j;
    if (n >= NN) continue;
    const int cn = cnt[n];
    const float inv = cn > 0 ? 1.0f / (float)cn : 0.0f;
    const float bsel = cn > 0 ? 1.0f : 0.0f;
    float4 o;
    o.x = fmaxf(0.f, (acc[j][0] * inv + bsel * bb.x) * sc[0] + sh[0]);
    o.y = fmaxf(0.f, (acc[j][1] * inv + bsel * bb.y) * sc[1] + sh[1]);
    o.z = fmaxf(0.f, (acc[j][2] * inv + bsel * bb.z) * sc[2] + sh[2]);
    o.w = fmaxf(0.f, (acc[j][3] * inv + bsel * bb.w) * sc[3] + sh[3]);
    *(float4*)(buf + (size_t)n * CC + cg * 4) = o;
  }
}

extern "C" void kernel_launch(void* const* d_in, const int* in_sizes, int n_in,
                              void* d_out, int out_size, void* d_ws, size_t ws_size,
                              hipStream_t stream) {
  const float* x     = (const float*)d_in[0];
  const int*   ei    = (const int*)d_in[1];
  const float* W     = (const float*)d_in[2];
  const float* bias  = (const float*)d_in[3];
  const float* gamma = (const float*)d_in[4];
  const float* beta  = (const float*)d_in[5];
  const float* rmean = (const float*)d_in[6];
  const float* rvar  = (const float*)d_in[7];
  float* out = (float*)d_out;

  // ws layout (bytes):
  //   off[NN+1] | bhist[256] | gcurz[256] (contiguous -> one 2KB memset)
  //   | csr[NE] | scsh[384f] | Wsw[16384 bf16] | ebuf int[NE] | h[NN*CC bf16]
  const size_t OFF_B  = 0;
  const size_t BH_B   = 400128;
  const size_t GC_B   = 401152;
  const size_t CSR_B  = 802304;
  const size_t SCSH_B = 7202304;
  const size_t WSW_B  = 7204352;
  const size_t EB_B   = 7237120;
  const size_t H1_B   = EB_B + (size_t)NE * 4;        // 13,637,120
  const size_t NEED1  = H1_B + (size_t)NN * CC * 2;   // 39,237,120
  const size_t NEED2  = EB_B + (size_t)NN * CC * 2;   // 32,837,120 (alias)

  const int GGRID = (NN + GNB - 1) / GNB;  // 1563 blocks (no slicing)

  if (ws_size >= NEED2) {
    int*   off   = (int*)((char*)d_ws + OFF_B);
    int*   bhist = (int*)((char*)d_ws + BH_B);
    int*   gcurz = (int*)((char*)d_ws + GC_B);
    int*   csr   = (int*)((char*)d_ws + CSR_B);
    float* scsh  = (float*)((char*)d_ws + SCSH_B);
    short* Wsw   = (short*)((char*)d_ws + WSW_B);

    hipMemsetAsync(bhist, 0, 2048, stream);  // bhist + gcurz
    prep_hist<<<ABLK, 256, 0, stream>>>(W, bias, gamma, beta, rmean, rvar,
                                        ei, Wsw, scsh, bhist);
    if (ws_size >= NEED1) {
      // tier 1: fused scatter+linear (ebuf and h distinct)
      int*   ebuf = (int*)((char*)d_ws + EB_B);
      short* h    = (short*)((char*)d_ws + H1_B);
      scatter_linear<<<ABLK + LBLK, 256, 0, stream>>>(
          ei, bhist, gcurz, ebuf, x, Wsw, scsh, h, ABLK);
      bucket_to_csr<<<NBUK, 1024, 0, stream>>>(ebuf, bhist, off, csr);
      gather_bn_relu<<<GGRID, 256, 0, stream>>>(h, off, csr, scsh, out);
    } else {
      // tier 2: un-fused, ebuf aliases h (r8-proven ordering)
      int*   ebuf = (int*)((char*)d_ws + EB_B);
      short* h    = (short*)((char*)d_ws + EB_B);
      scatter_linear<<<ABLK, 256, 0, stream>>>(
          ei, bhist, gcurz, ebuf, x, Wsw, scsh, h, ABLK);  // scatter only
      bucket_to_csr<<<NBUK, 1024, 0, stream>>>(ebuf, bhist, off, csr);
      scatter_linear<<<LBLK, 256, 0, stream>>>(
          ei, bhist, gcurz, ebuf, x, Wsw, scsh, h, 0);     // linear only
      gather_bn_relu<<<GGRID, 256, 0, stream>>>(h, off, csr, scsh, out);
    }
  } else {
    int* cnt = (int*)d_ws;
    hipMemsetAsync(out, 0, (size_t)NN * CC * sizeof(float), stream);
    hipMemsetAsync(cnt, 0, (size_t)NN * sizeof(int), stream);
    edge_scatter<<<(NE * 32) / 256, 256, 0, stream>>>(x, ei, out, cnt);
    gemm_bn_relu_fb<<<(NN + 63) / 64, 256, 0, stream>>>(
        out, W, bias, gamma, beta, rmean, rvar, cnt);
  }
}